// Round 1
// 485.955 us; speedup vs baseline: 1.1161x; 1.1161x over previous
//
#include <hip/hip_runtime.h>

typedef __bf16 bf16;
typedef __bf16 bf16x4 __attribute__((ext_vector_type(4)));
typedef __bf16 bf16x8 __attribute__((ext_vector_type(8)));
typedef float  floatx4 __attribute__((ext_vector_type(4)));

#define L_SEQ   2048
#define C_SEQ   256
#define S_SEQ   2304
#define NBATCH  4
#define NHEAD   16
#define DHEAD   64
#define DMODEL  1024
#define RMS_EPS 1.1920928955078125e-07f
#define LIN_EPS 1e-6f

// async global->LDS, 16B per lane; LDS dest is wave-uniform base + lane*16
__device__ __forceinline__ void gload_lds16(const void* g, void* l) {
  __builtin_amdgcn_global_load_lds(
      (const __attribute__((address_space(1))) void*)g,
      (__attribute__((address_space(3))) void*)l, 16, 0, 0);
}

// ---------------------------------------------------------------- transpose
// src: R x C f32 -> dst: C x R bf16 (fused convert)
__global__ __launch_bounds__(256) void transpose_f32_bf16(
    const float* __restrict__ src, bf16* __restrict__ dst, int R, int C) {
  __shared__ bf16 tile[32][33];
  int c0 = blockIdx.x * 32, r0 = blockIdx.y * 32;
  int tx = threadIdx.x & 31, ty = threadIdx.x >> 5;
  for (int i = ty; i < 32; i += 8)
    tile[i][tx] = (bf16)src[(size_t)(r0 + i) * C + c0 + tx];
  __syncthreads();
  for (int i = ty; i < 32; i += 8)
    dst[(size_t)(c0 + i) * R + r0 + tx] = tile[tx][i];
}

// ---------------------------------------------------------------- convert
// f32 -> bf16 streaming convert, 8 elems/thread
__global__ __launch_bounds__(256) void convert_bf16(
    const float* __restrict__ src, bf16* __restrict__ dst, size_t n) {
  size_t i = ((size_t)blockIdx.x * 256 + threadIdx.x) * 8;
  if (i >= n) return;
  floatx4 a = *(const floatx4*)(src + i);
  floatx4 b = *(const floatx4*)(src + i + 4);
  bf16x8 o;
#pragma unroll
  for (int j = 0; j < 4; j++) { o[j] = (bf16)a[j]; o[4 + j] = (bf16)b[j]; }
  *(bf16x8*)(dst + i) = o;
}

// ---------------------------------------------------------------- GEMM
// C = A[M][K] @ Bt[N][K]^T + bias[N]; A,B bf16; fp32 accum; bf16 out.
// m97 structure: linear LDS [128][32], global_load_lds width-16 staging,
// 2 barriers per K-step, 4 waves, 4x4 mfma_16x16x32_bf16 per wave.
// SCATTER=true: col -> (which={q,k,v}, h, dh), row -> (b, s) head-major slabs.
template <bool SCATTER>
__global__ __launch_bounds__(256) void gemm_bias(
    const bf16* __restrict__ A, const bf16* __restrict__ Bt,
    const float* __restrict__ bias, bf16* __restrict__ C0,
    bf16* __restrict__ qs, bf16* __restrict__ ks, bf16* __restrict__ vs,
    int M, int N, int K, int rpb_shift, int seq_off) {
  __shared__ bf16 As[128 * 32];   // linear: 64B rows (global_load_lds dest)
  __shared__ bf16 Bs[128 * 32];
  int n0 = blockIdx.x * 128, m0 = blockIdx.y * 128;
  int t = threadIdx.x;
  int lane = t & 63, w = t >> 6;
  int wm = (w & 1) * 64, wn = (w >> 1) * 64;
  int l16 = lane & 15, l4 = lane >> 4;

  // staging geometry: chunk = w*2+j covers 1024 B = 16 rows; lane l covers
  // row chunk*16 + l/4, elems (l&3)*8 .. +7  (16 B)
  int srow = w * 32 + (lane >> 2);            // j=0 row; j=1 adds 16
  int scol = (lane & 3) * 8;
  const bf16* Ab = A  + (size_t)(m0 + srow) * K + scol;
  const bf16* Bb = Bt + (size_t)(n0 + srow) * K + scol;

  floatx4 acc[4][4] = {};
  for (int kb = 0; kb < K; kb += 32) {
    __syncthreads();                 // protect prior iter's LDS reads
#pragma unroll
    for (int j = 0; j < 2; j++) {
      gload_lds16(Ab + (size_t)j * 16 * K + kb, (char*)As + (w * 2 + j) * 1024);
      gload_lds16(Bb + (size_t)j * 16 * K + kb, (char*)Bs + (w * 2 + j) * 1024);
    }
    __syncthreads();                 // vmcnt(0) drain emitted before barrier
    bf16x8 af[4], bfr[4];
#pragma unroll
    for (int i = 0; i < 4; i++) {
      af[i]  = *(const bf16x8*)&As[(wm + i * 16 + l16) * 32 + l4 * 8];
      bfr[i] = *(const bf16x8*)&Bs[(wn + i * 16 + l16) * 32 + l4 * 8];
    }
#pragma unroll
    for (int i = 0; i < 4; i++)
#pragma unroll
      for (int j = 0; j < 4; j++)
        acc[i][j] = __builtin_amdgcn_mfma_f32_16x16x32_bf16(af[i], bfr[j], acc[i][j], 0, 0, 0);
  }
  // epilogue: D[row=(l>>4)*4+r][col=l&15] per 16x16 tile
#pragma unroll
  for (int i = 0; i < 4; i++)
#pragma unroll
    for (int j = 0; j < 4; j++) {
      int col = n0 + wn + j * 16 + l16;
      float bval = bias[col];
      if constexpr (SCATTER) {
        int which = col >> 10;
        int h = (col >> 6) & 15;
        int dh = col & 63;
        bf16* dst = which == 0 ? qs : (which == 1 ? ks : vs);
        int rmask = (1 << rpb_shift) - 1;
#pragma unroll
        for (int r = 0; r < 4; r++) {
          int rw = m0 + wm + i * 16 + l4 * 4 + r;
          int b = rw >> rpb_shift;
          int s = seq_off + (rw & rmask);
          dst[((size_t)(b * NHEAD + h) * S_SEQ + s) * DHEAD + dh] =
              (bf16)(acc[i][j][r] + bval);
        }
      } else {
#pragma unroll
        for (int r = 0; r < 4; r++) {
          int rw = m0 + wm + i * 16 + l4 * 4 + r;
          C0[(size_t)rw * N + col] = (bf16)(acc[i][j][r] + bval);
        }
      }
    }
}

// ---------------------------------------------------------------- anymask
__global__ __launch_bounds__(256) void anymask_kernel(
    const int* __restrict__ mask, int* __restrict__ anym) {
  int b = blockIdx.x, t = threadIdx.x;
  int a = 0;
  size_t base = (size_t)b * L_SEQ * L_SEQ;      // row 0 of batch b
  for (int j = t; j < L_SEQ; j += 256) a |= mask[base + j];
  __shared__ int sh;
  if (t == 0) sh = 0;
  __syncthreads();
  if (a) atomicOr(&sh, 1);
  __syncthreads();
  if (t == 0) anym[b] = sh;
}

__global__ __launch_bounds__(256) void zero_f32(float* __restrict__ p, int n) {
  for (int i = blockIdx.x * 256 + threadIdx.x; i < n; i += gridDim.x * 256)
    p[i] = 0.f;
}

// ---------------------------------------------------------------- qkv post
// One block per token (9216). In-place on head-major q/k slabs: rmsnorm over
// D=1024, RoPE (x tokens only), relu; key-mask on k.
__global__ __launch_bounds__(256) void qkv_post(
    bf16* __restrict__ qs, bf16* __restrict__ ks,
    const int* __restrict__ mask, const int* __restrict__ spos,
    const int* __restrict__ anym,
    const float* __restrict__ g_q, const float* __restrict__ g_k,
    const float* __restrict__ cg_q, const float* __restrict__ cg_k) {
  int g = blockIdx.x, t = threadIdx.x;
  bool is_ctx = g >= NBATCH * L_SEQ;
  int b, s;
  const float *gq, *gk;
  float mval;
  if (!is_ctx) {
    b = g >> 11;
    int l = g & 2047;
    s = l;
    mval = mask[(size_t)b * L_SEQ * L_SEQ + l] ? 1.f : 0.f;  // mask[b][0][l]
    gq = g_q; gk = g_k;
  } else {
    int gg = g - NBATCH * L_SEQ;
    b = gg >> 8;
    s = L_SEQ + (gg & 255);
    mval = anym[b] ? 1.f : 0.f;
    gq = cg_q; gk = cg_k;
  }
  int d0 = t * 4;
  int h = t >> 4, dh = (t & 15) * 4;            // h*64+dh == d0
  size_t base = ((size_t)(b * NHEAD + h) * S_SEQ + s) * DHEAD + dh;
  bf16x4 q4 = *(const bf16x4*)(qs + base);
  bf16x4 k4 = *(const bf16x4*)(ks + base);
  float qv[4], kv[4], pq = 0.f, pk = 0.f;
#pragma unroll
  for (int i = 0; i < 4; i++) {
    qv[i] = (float)q4[i]; kv[i] = (float)k4[i];
    pq += qv[i] * qv[i];  pk += kv[i] * kv[i];
  }
  int lane = t & 63, w = t >> 6;
  for (int off = 32; off > 0; off >>= 1) {
    pq += __shfl_down(pq, off, 64);
    pk += __shfl_down(pk, off, 64);
  }
  __shared__ float red[8];
  if (lane == 0) { red[w] = pq; red[4 + w] = pk; }
  __syncthreads();
  float sq = red[0] + red[1] + red[2] + red[3];
  float sk = red[4] + red[5] + red[6] + red[7];
  float scq = rsqrtf(sq * (1.f / DMODEL) + RMS_EPS);
  float sck = rsqrtf(sk * (1.f / DMODEL) + RMS_EPS);
#pragma unroll
  for (int i = 0; i < 4; i++) {
    qv[i] *= scq * gq[d0 + i];
    kv[i] *= sck * gk[d0 + i];
  }
  if (!is_ctx) {
    float p = (float)(spos[b] + s);
#pragma unroll
    for (int pr = 0; pr < 2; pr++) {
      int fi = (dh >> 1) + pr;                              // freq 0..31
      float ang = p * expf((float)fi * -0.28782313662425572f);  // ln(1e4)/32
      float cc = cosf(ang), ss = sinf(ang);
      float t0 = qv[2 * pr], t1 = qv[2 * pr + 1];
      qv[2 * pr]     = t0 * cc - t1 * ss;
      qv[2 * pr + 1] = t0 * ss + t1 * cc;
      t0 = kv[2 * pr]; t1 = kv[2 * pr + 1];
      kv[2 * pr]     = t0 * cc - t1 * ss;
      kv[2 * pr + 1] = t0 * ss + t1 * cc;
    }
  }
  bf16x4 qo, ko;
#pragma unroll
  for (int i = 0; i < 4; i++) {
    qo[i] = (bf16)fmaxf(qv[i], 0.f);
    ko[i] = (bf16)(fmaxf(kv[i], 0.f) * mval);
  }
  *(bf16x4*)(qs + base) = qo;
  *(bf16x4*)(ks + base) = ko;
}

// ---------------------------------------------------------------- vk accum
// vk[bh][e][d] = sum_s vpad[s][e]*kf[s][d]; e=64 row = sum_s kf[s][d].
__global__ __launch_bounds__(256) void vk_accum(
    const bf16* __restrict__ kf, const bf16* __restrict__ v,
    float* __restrict__ vk) {
  int bh = blockIdx.x >> 2, chunk = blockIdx.x & 3;
  int t = threadIdx.x;
  int d = t & 63, eg = t >> 6, e0 = eg * 16;
  const bf16* kfp = kf + (size_t)bh * S_SEQ * DHEAD;
  const bf16* vp  = v  + (size_t)bh * S_SEQ * DHEAD;
  float acc[16] = {};
  float dacc = 0.f;
  int s0 = chunk * 576, s1 = s0 + 576;
  for (int s = s0; s < s1; s++) {
    float kval = (float)kfp[(size_t)s * DHEAD + d];
    bf16x8 va = *(const bf16x8*)(vp + (size_t)s * DHEAD + e0);
    bf16x8 vb = *(const bf16x8*)(vp + (size_t)s * DHEAD + e0 + 8);
#pragma unroll
    for (int i = 0; i < 8; i++) acc[i] += (float)va[i] * kval;
#pragma unroll
    for (int i = 0; i < 8; i++) acc[8 + i] += (float)vb[i] * kval;
    dacc += kval;
  }
  float* vkbh = vk + (size_t)bh * 65 * 64;
#pragma unroll
  for (int i = 0; i < 16; i++) atomicAdd(&vkbh[(e0 + i) * 64 + d], acc[i]);
  if (eg == 0) atomicAdd(&vkbh[64 * 64 + d], dacc);
}

// ---------------------------------------------------------------- res + div
// res[q][e] = sum_d qf[q][d]*vk[e][d]; attn = res[:,:64]/(res[:,64]+eps).
__global__ __launch_bounds__(256) void res_attn(
    const bf16* __restrict__ qf, const float* __restrict__ vk,
    bf16* __restrict__ attn_x, bf16* __restrict__ attn_c) {
  __shared__ bf16 Bs[80][72];
  __shared__ float sden[256];
  int bh = blockIdx.x / 9, mblk = blockIdx.x % 9;
  int b = bh >> 4, h = bh & 15;
  int t = threadIdx.x, lane = t & 63, w = t >> 6;
  const float* vkp = vk + (size_t)bh * 65 * 64;
  for (int i = t; i < 80 * 64; i += 256) {
    int e = i >> 6, d = i & 63;
    Bs[e][d] = (bf16)(e < 65 ? vkp[i] : 0.f);
  }
  __syncthreads();
  int l16 = lane & 15, l4 = lane >> 4;
  const bf16* qbase = qf + (size_t)bh * S_SEQ * DHEAD;
  int q0w = mblk * 256 + w * 64;

  floatx4 acc[4][5] = {};
  bf16x8 af[4][2], bfr[5][2];
#pragma unroll
  for (int mt = 0; mt < 4; mt++) {
    int q = q0w + mt * 16 + l16;
    af[mt][0] = *(const bf16x8*)(qbase + (size_t)q * 64 + l4 * 8);
    af[mt][1] = *(const bf16x8*)(qbase + (size_t)q * 64 + 32 + l4 * 8);
  }
#pragma unroll
  for (int nt = 0; nt < 5; nt++) {
    bfr[nt][0] = *(const bf16x8*)&Bs[nt * 16 + l16][l4 * 8];
    bfr[nt][1] = *(const bf16x8*)&Bs[nt * 16 + l16][32 + l4 * 8];
  }
#pragma unroll
  for (int mt = 0; mt < 4; mt++)
#pragma unroll
    for (int nt = 0; nt < 5; nt++) {
      acc[mt][nt] = __builtin_amdgcn_mfma_f32_16x16x32_bf16(af[mt][0], bfr[nt][0], acc[mt][nt], 0, 0, 0);
      acc[mt][nt] = __builtin_amdgcn_mfma_f32_16x16x32_bf16(af[mt][1], bfr[nt][1], acc[mt][nt], 0, 0, 0);
    }
  // denominator: e=64 = col 0 of n-tile 4 (lanes with l16==0)
  if (l16 == 0) {
#pragma unroll
    for (int mt = 0; mt < 4; mt++)
#pragma unroll
      for (int r = 0; r < 4; r++)
        sden[w * 64 + mt * 16 + l4 * 4 + r] = acc[mt][4][r];
  }
  __syncthreads();
#pragma unroll
  for (int mt = 0; mt < 4; mt++)
#pragma unroll
    for (int r = 0; r < 4; r++) {
      float den = sden[w * 64 + mt * 16 + l4 * 4 + r] + LIN_EPS;
      float rden = 1.f / den;
      int q = q0w + mt * 16 + l4 * 4 + r;
#pragma unroll
      for (int nt = 0; nt < 4; nt++) {
        int dcol = nt * 16 + l16;
        float a = acc[mt][nt][r] * rden;
        if (q < L_SEQ)
          attn_x[((size_t)b * L_SEQ + q) * DMODEL + h * DHEAD + dcol] = (bf16)a;
        else
          attn_c[((size_t)b * C_SEQ + (q - L_SEQ)) * DMODEL + h * DHEAD + dcol] = (bf16)a;
      }
    }
}

// ---------------------------------------------------------------- final norm
// Reads bf16 y, writes FLOAT32 output (the reference's output dtype).
__global__ __launch_bounds__(256) void final_norm(
    const bf16* __restrict__ y_x, const bf16* __restrict__ y_c,
    const float* __restrict__ g_out, const float* __restrict__ cg_out,
    float* __restrict__ out) {
  int g = blockIdx.x, t = threadIdx.x;
  const bf16* src;
  const float* gv;
  if (g < NBATCH * L_SEQ) {
    src = y_x + (size_t)g * DMODEL; gv = g_out;
  } else {
    int gg = g - NBATCH * L_SEQ;
    src = y_c + (size_t)gg * DMODEL; gv = cg_out;
  }
  float* dst = out + (size_t)g * DMODEL;
  int d0 = t * 4;
  bf16x4 y4 = *(const bf16x4*)(src + d0);
  float yv[4], p = 0.f;
#pragma unroll
  for (int i = 0; i < 4; i++) { yv[i] = (float)y4[i]; p += yv[i] * yv[i]; }
  int lane = t & 63, w = t >> 6;
  for (int off = 32; off > 0; off >>= 1) p += __shfl_down(p, off, 64);
  __shared__ float red[4];
  if (lane == 0) red[w] = p;
  __syncthreads();
  float ssum = red[0] + red[1] + red[2] + red[3];
  float sc = rsqrtf(ssum * (1.f / DMODEL) + RMS_EPS);
  floatx4 o;
#pragma unroll
  for (int i = 0; i < 4; i++) o[i] = yv[i] * sc * gv[d0 + i];
  *(floatx4*)(dst + d0) = o;
}

// ---------------------------------------------------------------- launch
extern "C" void kernel_launch(void* const* d_in, const int* in_sizes, int n_in,
                              void* d_out, int out_size, void* d_ws, size_t ws_size,
                              hipStream_t stream) {
  const float* x      = (const float*)d_in[0];
  const float* ctx    = (const float*)d_in[1];
  const int*   mask   = (const int*)d_in[2];
  const int*   spos   = (const int*)d_in[3];
  const float* Wqkv   = (const float*)d_in[4];
  const float* bqkv   = (const float*)d_in[5];
  const float* g_q    = (const float*)d_in[6];
  const float* g_k    = (const float*)d_in[7];
  const float* cWqkv  = (const float*)d_in[8];
  const float* cbqkv  = (const float*)d_in[9];
  const float* cg_q   = (const float*)d_in[10];
  const float* cg_k   = (const float*)d_in[11];
  const float* Wout   = (const float*)d_in[12];
  const float* bout   = (const float*)d_in[13];
  const float* g_out  = (const float*)d_in[14];
  const float* cWout  = (const float*)d_in[15];
  const float* cbout  = (const float*)d_in[16];
  const float* cg_out = (const float*)d_in[17];

  char* wsp = (char*)d_ws;
  size_t off = 0;
  auto alloc = [&](size_t bytes) -> void* {
    void* p = wsp + off;
    off += (bytes + 255) & ~(size_t)255;
    return p;
  };
  bf16* WqkvT  = (bf16*)alloc((size_t)3072 * 1024 * 2);
  bf16* cWqkvT = (bf16*)alloc((size_t)3072 * 1024 * 2);
  bf16* WoutT  = (bf16*)alloc((size_t)1024 * 1024 * 2);
  bf16* cWoutT = (bf16*)alloc((size_t)1024 * 1024 * 2);
  bf16* xbf    = (bf16*)alloc((size_t)NBATCH * L_SEQ * DMODEL * 2);
  bf16* cbf    = (bf16*)alloc((size_t)NBATCH * C_SEQ * DMODEL * 2);
  const size_t SLAB = (size_t)NBATCH * NHEAD * S_SEQ * DHEAD;  // 9,437,184
  bf16* qfs    = (bf16*)alloc(SLAB * 2);
  bf16* kfs    = (bf16*)alloc(SLAB * 2);
  bf16* vfs    = (bf16*)alloc(SLAB * 2);
  float* vkw   = (float*)alloc((size_t)64 * 65 * 64 * 4);
  int* anym    = (int*)alloc(256);
  // attn aliases kf slab (dead after vk_accum); y aliases v slab.
  bf16* attn_x = kfs;
  bf16* attn_c = kfs + (size_t)NBATCH * L_SEQ * DMODEL;
  bf16* y_x    = vfs;
  bf16* y_c    = vfs + (size_t)NBATCH * L_SEQ * DMODEL;

  // 1) weight transposes+convert (N x K bf16 for MFMA B-operand) + activation
  //    f32->bf16 converts (hoisted out of the GEMM to enable global_load_lds)
  transpose_f32_bf16<<<dim3(96, 32), 256, 0, stream>>>(Wqkv, WqkvT, 1024, 3072);
  transpose_f32_bf16<<<dim3(96, 32), 256, 0, stream>>>(cWqkv, cWqkvT, 1024, 3072);
  transpose_f32_bf16<<<dim3(32, 32), 256, 0, stream>>>(Wout, WoutT, 1024, 1024);
  transpose_f32_bf16<<<dim3(32, 32), 256, 0, stream>>>(cWout, cWoutT, 1024, 1024);
  convert_bf16<<<4096, 256, 0, stream>>>(x, xbf, (size_t)NBATCH * L_SEQ * DMODEL);
  convert_bf16<<<512, 256, 0, stream>>>(ctx, cbf, (size_t)NBATCH * C_SEQ * DMODEL);

  // 2) QKV projections -> head-major q/k/v slabs
  gemm_bias<true><<<dim3(24, 64), 256, 0, stream>>>(
      xbf, WqkvT, bqkv, nullptr, qfs, kfs, vfs, 8192, 3072, 1024, 11, 0);
  gemm_bias<true><<<dim3(24, 8), 256, 0, stream>>>(
      cbf, cWqkvT, cbqkv, nullptr, qfs, kfs, vfs, 1024, 3072, 1024, 8, L_SEQ);

  // 3) mask helper + zero vk accumulator
  anymask_kernel<<<4, 256, 0, stream>>>(mask, anym);
  zero_f32<<<1040, 256, 0, stream>>>(vkw, 64 * 65 * 64);

  // 4) in-place rmsnorm + rope + relu + mask on q/k slabs
  qkv_post<<<NBATCH * (L_SEQ + C_SEQ), 256, 0, stream>>>(
      qfs, kfs, mask, spos, anym, g_q, g_k, cg_q, cg_k);

  // 5) vk = vpad^T kf
  vk_accum<<<256, 256, 0, stream>>>(kfs, vfs, vkw);

  // 6) res = qf vk^T, divide, scatter to token-major (B,S,D)
  res_attn<<<576, 256, 0, stream>>>(qfs, vkw, attn_x, attn_c);

  // 7) output projections
  gemm_bias<false><<<dim3(8, 64), 256, 0, stream>>>(
      attn_x, WoutT, bout, y_x, nullptr, nullptr, nullptr, 8192, 1024, 1024, 0, 0);
  gemm_bias<false><<<dim3(8, 8), 256, 0, stream>>>(
      attn_c, cWoutT, cbout, y_c, nullptr, nullptr, nullptr, 1024, 1024, 1024, 0, 0);

  // 8) final rmsnorm -> FLOAT32 d_out (x_out rows then c_out rows)
  final_norm<<<NBATCH * (L_SEQ + C_SEQ), 256, 0, stream>>>(
      y_x, y_c, g_out, cg_out, (float*)d_out);
}

// Round 2
// 410.807 us; speedup vs baseline: 1.3203x; 1.1829x over previous
//
#include <hip/hip_runtime.h>

typedef __bf16 bf16;
typedef __bf16 bf16x4 __attribute__((ext_vector_type(4)));
typedef __bf16 bf16x8 __attribute__((ext_vector_type(8)));
typedef float  floatx4 __attribute__((ext_vector_type(4)));

#define L_SEQ   2048
#define C_SEQ   256
#define S_SEQ   2304
#define NBATCH  4
#define NHEAD   16
#define DHEAD   64
#define DMODEL  1024
#define RMS_EPS 1.1920928955078125e-07f
#define LIN_EPS 1e-6f

// async global->LDS, 16B per lane; LDS dest is wave-uniform base + lane*16
__device__ __forceinline__ void gload_lds16(const void* g, void* l) {
  __builtin_amdgcn_global_load_lds(
      (const __attribute__((address_space(1))) void*)g,
      (__attribute__((address_space(3))) void*)l, 16, 0, 0);
}

// ---------------------------------------------------------------- transpose
// src: R x C f32 -> dst: C x R bf16 (fused convert)
__global__ __launch_bounds__(256) void transpose_f32_bf16(
    const float* __restrict__ src, bf16* __restrict__ dst, int R, int C) {
  __shared__ bf16 tile[32][33];
  int c0 = blockIdx.x * 32, r0 = blockIdx.y * 32;
  int tx = threadIdx.x & 31, ty = threadIdx.x >> 5;
  for (int i = ty; i < 32; i += 8)
    tile[i][tx] = (bf16)src[(size_t)(r0 + i) * C + c0 + tx];
  __syncthreads();
  for (int i = ty; i < 32; i += 8)
    dst[(size_t)(c0 + i) * R + r0 + tx] = tile[tx][i];
}

// ---------------------------------------------------------------- convert
// f32 -> bf16 streaming convert, 8 elems/thread
__global__ __launch_bounds__(256) void convert_bf16(
    const float* __restrict__ src, bf16* __restrict__ dst, size_t n) {
  size_t i = ((size_t)blockIdx.x * 256 + threadIdx.x) * 8;
  if (i >= n) return;
  floatx4 a = *(const floatx4*)(src + i);
  floatx4 b = *(const floatx4*)(src + i + 4);
  bf16x8 o;
#pragma unroll
  for (int j = 0; j < 4; j++) { o[j] = (bf16)a[j]; o[4 + j] = (bf16)b[j]; }
  *(bf16x8*)(dst + i) = o;
}

// ---------------------------------------------------------------- GEMM
// C = A[M][K] @ Bt[N][K]^T + bias[N]; A,B bf16; fp32 accum; bf16 out.
// m97 structure: linear LDS [128][32], global_load_lds width-16 staging,
// 2 barriers per K-step, 4 waves, 4x4 mfma_16x16x32_bf16 per wave.
// SCATTER=true: col -> (which={q,k,v}, h, dh), row -> (b, s) head-major slabs.
// q/k written [bh][s][dh]; v written TRANSPOSED [bh][dh][s] (feeds vk_mfma
// A-operand directly; per-lane r=0..3 are consecutive s -> bf16x4 store).
template <bool SCATTER>
__global__ __launch_bounds__(256) void gemm_bias(
    const bf16* __restrict__ A, const bf16* __restrict__ Bt,
    const float* __restrict__ bias, bf16* __restrict__ C0,
    bf16* __restrict__ qs, bf16* __restrict__ ks, bf16* __restrict__ vs,
    int M, int N, int K, int rpb_shift, int seq_off) {
  __shared__ bf16 As[128 * 32];   // linear: 64B rows (global_load_lds dest)
  __shared__ bf16 Bs[128 * 32];
  int n0 = blockIdx.x * 128, m0 = blockIdx.y * 128;
  int t = threadIdx.x;
  int lane = t & 63, w = t >> 6;
  int wm = (w & 1) * 64, wn = (w >> 1) * 64;
  int l16 = lane & 15, l4 = lane >> 4;

  // staging geometry: chunk = w*2+j covers 1024 B = 16 rows; lane l covers
  // row chunk*16 + l/4, elems (l&3)*8 .. +7  (16 B)
  int srow = w * 32 + (lane >> 2);            // j=0 row; j=1 adds 16
  int scol = (lane & 3) * 8;
  const bf16* Ab = A  + (size_t)(m0 + srow) * K + scol;
  const bf16* Bb = Bt + (size_t)(n0 + srow) * K + scol;

  floatx4 acc[4][4] = {};
  for (int kb = 0; kb < K; kb += 32) {
    __syncthreads();                 // protect prior iter's LDS reads
#pragma unroll
    for (int j = 0; j < 2; j++) {
      gload_lds16(Ab + (size_t)j * 16 * K + kb, (char*)As + (w * 2 + j) * 1024);
      gload_lds16(Bb + (size_t)j * 16 * K + kb, (char*)Bs + (w * 2 + j) * 1024);
    }
    __syncthreads();                 // vmcnt(0) drain emitted before barrier
    bf16x8 af[4], bfr[4];
#pragma unroll
    for (int i = 0; i < 4; i++) {
      af[i]  = *(const bf16x8*)&As[(wm + i * 16 + l16) * 32 + l4 * 8];
      bfr[i] = *(const bf16x8*)&Bs[(wn + i * 16 + l16) * 32 + l4 * 8];
    }
#pragma unroll
    for (int i = 0; i < 4; i++)
#pragma unroll
      for (int j = 0; j < 4; j++)
        acc[i][j] = __builtin_amdgcn_mfma_f32_16x16x32_bf16(af[i], bfr[j], acc[i][j], 0, 0, 0);
  }
  // epilogue: D[row=(l>>4)*4+r][col=l&15] per 16x16 tile
#pragma unroll
  for (int i = 0; i < 4; i++)
#pragma unroll
    for (int j = 0; j < 4; j++) {
      int col = n0 + wn + j * 16 + l16;
      float bval = bias[col];
      if constexpr (SCATTER) {
        int which = col >> 10;
        int h = (col >> 6) & 15;
        int dh = col & 63;
        int rmask = (1 << rpb_shift) - 1;
        if (which == 2) {
          // v transposed: [bh][dh][s]; r=0..3 are s, s+1, s+2, s+3
          int rw0 = m0 + wm + i * 16 + l4 * 4;
          int b = rw0 >> rpb_shift;
          int s = seq_off + (rw0 & rmask);
          bf16x4 o;
#pragma unroll
          for (int r = 0; r < 4; r++) o[r] = (bf16)(acc[i][j][r] + bval);
          *(bf16x4*)(vs + ((size_t)(b * NHEAD + h) * DHEAD + dh) * S_SEQ + s) = o;
        } else {
          bf16* dst = which == 0 ? qs : ks;
#pragma unroll
          for (int r = 0; r < 4; r++) {
            int rw = m0 + wm + i * 16 + l4 * 4 + r;
            int b = rw >> rpb_shift;
            int s = seq_off + (rw & rmask);
            dst[((size_t)(b * NHEAD + h) * S_SEQ + s) * DHEAD + dh] =
                (bf16)(acc[i][j][r] + bval);
          }
        }
      } else {
#pragma unroll
        for (int r = 0; r < 4; r++) {
          int rw = m0 + wm + i * 16 + l4 * 4 + r;
          C0[(size_t)rw * N + col] = (bf16)(acc[i][j][r] + bval);
        }
      }
    }
}

// ---------------------------------------------------------------- anymask
__global__ __launch_bounds__(256) void anymask_kernel(
    const int* __restrict__ mask, int* __restrict__ anym) {
  int b = blockIdx.x, t = threadIdx.x;
  int a = 0;
  size_t base = (size_t)b * L_SEQ * L_SEQ;      // row 0 of batch b
  for (int j = t; j < L_SEQ; j += 256) a |= mask[base + j];
  __shared__ int sh;
  if (t == 0) sh = 0;
  __syncthreads();
  if (a) atomicOr(&sh, 1);
  __syncthreads();
  if (t == 0) anym[b] = sh;
}

__global__ __launch_bounds__(256) void zero_f32(float* __restrict__ p, int n) {
  for (int i = blockIdx.x * 256 + threadIdx.x; i < n; i += gridDim.x * 256)
    p[i] = 0.f;
}

// ---------------------------------------------------------------- qkv post
// One block per token (9216). In-place on head-major q/k slabs: rmsnorm over
// D=1024, RoPE (x tokens only), relu; key-mask on k.
__global__ __launch_bounds__(256) void qkv_post(
    bf16* __restrict__ qs, bf16* __restrict__ ks,
    const int* __restrict__ mask, const int* __restrict__ spos,
    const int* __restrict__ anym,
    const float* __restrict__ g_q, const float* __restrict__ g_k,
    const float* __restrict__ cg_q, const float* __restrict__ cg_k) {
  int g = blockIdx.x, t = threadIdx.x;
  bool is_ctx = g >= NBATCH * L_SEQ;
  int b, s;
  const float *gq, *gk;
  float mval;
  if (!is_ctx) {
    b = g >> 11;
    int l = g & 2047;
    s = l;
    mval = mask[(size_t)b * L_SEQ * L_SEQ + l] ? 1.f : 0.f;  // mask[b][0][l]
    gq = g_q; gk = g_k;
  } else {
    int gg = g - NBATCH * L_SEQ;
    b = gg >> 8;
    s = L_SEQ + (gg & 255);
    mval = anym[b] ? 1.f : 0.f;
    gq = cg_q; gk = cg_k;
  }
  int d0 = t * 4;
  int h = t >> 4, dh = (t & 15) * 4;            // h*64+dh == d0
  size_t base = ((size_t)(b * NHEAD + h) * S_SEQ + s) * DHEAD + dh;
  bf16x4 q4 = *(const bf16x4*)(qs + base);
  bf16x4 k4 = *(const bf16x4*)(ks + base);
  float qv[4], kv[4], pq = 0.f, pk = 0.f;
#pragma unroll
  for (int i = 0; i < 4; i++) {
    qv[i] = (float)q4[i]; kv[i] = (float)k4[i];
    pq += qv[i] * qv[i];  pk += kv[i] * kv[i];
  }
  int lane = t & 63, w = t >> 6;
  for (int off = 32; off > 0; off >>= 1) {
    pq += __shfl_down(pq, off, 64);
    pk += __shfl_down(pk, off, 64);
  }
  __shared__ float red[8];
  if (lane == 0) { red[w] = pq; red[4 + w] = pk; }
  __syncthreads();
  float sq = red[0] + red[1] + red[2] + red[3];
  float sk = red[4] + red[5] + red[6] + red[7];
  float scq = rsqrtf(sq * (1.f / DMODEL) + RMS_EPS);
  float sck = rsqrtf(sk * (1.f / DMODEL) + RMS_EPS);
#pragma unroll
  for (int i = 0; i < 4; i++) {
    qv[i] *= scq * gq[d0 + i];
    kv[i] *= sck * gk[d0 + i];
  }
  if (!is_ctx) {
    float p = (float)(spos[b] + s);
#pragma unroll
    for (int pr = 0; pr < 2; pr++) {
      int fi = (dh >> 1) + pr;                              // freq 0..31
      float ang = p * expf((float)fi * -0.28782313662425572f);  // ln(1e4)/32
      float cc = cosf(ang), ss = sinf(ang);
      float t0 = qv[2 * pr], t1 = qv[2 * pr + 1];
      qv[2 * pr]     = t0 * cc - t1 * ss;
      qv[2 * pr + 1] = t0 * ss + t1 * cc;
      t0 = kv[2 * pr]; t1 = kv[2 * pr + 1];
      kv[2 * pr]     = t0 * cc - t1 * ss;
      kv[2 * pr + 1] = t0 * ss + t1 * cc;
    }
  }
  bf16x4 qo, ko;
#pragma unroll
  for (int i = 0; i < 4; i++) {
    qo[i] = (bf16)fmaxf(qv[i], 0.f);
    ko[i] = (bf16)(fmaxf(kv[i], 0.f) * mval);
  }
  *(bf16x4*)(qs + base) = qo;
  *(bf16x4*)(ks + base) = ko;
}

// ---------------------------------------------------------------- vk (MFMA)
// vk[bh][e][d] = sum_s vT[bh][e][s] * kf[bh][s][d]; row e=64: sum_s kf[s][d].
// Grid: 64 bh x 8 chunks (512 blocks); 4 waves; wave w owns e-rows
// [w*16, w*16+16). Per K-step (32 s): stage vT tile [64][40] (vector LDS
// writes) + kf tile reg-transposed to Ks[d][s] [64][40]; 4 MFMAs per wave.
// 80 B rows: 20-bank stride, 16B-aligned b128 reads. Partials atomicAdd'ed
// into the zeroed vkw accumulator.
#define VK_CH   8
#define VK_SPAN (S_SEQ / VK_CH)   // 288 = 9 K-steps of 32
__global__ __launch_bounds__(256) void vk_mfma(
    const bf16* __restrict__ vT, const bf16* __restrict__ kf,
    float* __restrict__ vk) {
  __shared__ bf16 Vs[64][40];
  __shared__ bf16 Ks[64][40];      // Ks[d][s]
  int bh = blockIdx.x >> 3, chunk = blockIdx.x & 7;
  int t = threadIdx.x, lane = t & 63, w = t >> 6;
  int l16 = lane & 15, l4 = lane >> 4;
  const bf16* vp = vT + (size_t)bh * DHEAD * S_SEQ;
  const bf16* kp = kf + (size_t)bh * S_SEQ * DHEAD;
  int s_begin = chunk * VK_SPAN;
  int ve = t >> 2, vso = (t & 3) * 8;        // v staging: row e, col offset
  int ks_s = t & 31, kd0 = (t >> 5) * 8;     // kf staging: s-slice, d-octet
  floatx4 acc[4] = {};
  float dsum[8] = {};                         // denom partials, d=kd0..kd0+7
  for (int st = 0; st < VK_SPAN; st += 32) {
    int s0 = s_begin + st;
    bf16x8 vv = *(const bf16x8*)(vp + (size_t)ve * S_SEQ + s0 + vso);
    bf16x8 kv = *(const bf16x8*)(kp + (size_t)(s0 + ks_s) * DHEAD + kd0);
    __syncthreads();               // protect prior iter's LDS reads
    *(bf16x8*)&Vs[ve][vso] = vv;
#pragma unroll
    for (int j = 0; j < 8; j++) {
      Ks[kd0 + j][ks_s] = kv[j];
      dsum[j] += (float)kv[j];
    }
    __syncthreads();
    bf16x8 af = *(const bf16x8*)&Vs[w * 16 + l16][l4 * 8];
#pragma unroll
    for (int nt = 0; nt < 4; nt++) {
      bf16x8 bfr = *(const bf16x8*)&Ks[nt * 16 + l16][l4 * 8];
      acc[nt] = __builtin_amdgcn_mfma_f32_16x16x32_bf16(af, bfr, acc[nt], 0, 0, 0);
    }
  }
  float* vkbh = vk + (size_t)bh * 65 * 64;
#pragma unroll
  for (int nt = 0; nt < 4; nt++)
#pragma unroll
    for (int r = 0; r < 4; r++)
      atomicAdd(&vkbh[(w * 16 + l4 * 4 + r) * 64 + nt * 16 + l16], acc[nt][r]);
  // denom: reduce within each 32-lane half-wave (each owns one d-octet)
#pragma unroll
  for (int j = 0; j < 8; j++)
#pragma unroll
    for (int off = 16; off > 0; off >>= 1)
      dsum[j] += __shfl_down(dsum[j], off, 32);
  if ((lane & 31) == 0)
#pragma unroll
    for (int j = 0; j < 8; j++)
      atomicAdd(&vkbh[64 * 64 + kd0 + j], dsum[j]);
}

// ---------------------------------------------------------------- res + div
// res[q][e] = sum_d qf[q][d]*vk[e][d]; attn = res[:,:64]/(res[:,64]+eps).
__global__ __launch_bounds__(256) void res_attn(
    const bf16* __restrict__ qf, const float* __restrict__ vk,
    bf16* __restrict__ attn_x, bf16* __restrict__ attn_c) {
  __shared__ bf16 Bs[80][72];
  __shared__ float sden[256];
  int bh = blockIdx.x / 9, mblk = blockIdx.x % 9;
  int b = bh >> 4, h = bh & 15;
  int t = threadIdx.x, lane = t & 63, w = t >> 6;
  const float* vkp = vk + (size_t)bh * 65 * 64;
  for (int i = t; i < 80 * 64; i += 256) {
    int e = i >> 6, d = i & 63;
    Bs[e][d] = (bf16)(e < 65 ? vkp[i] : 0.f);
  }
  __syncthreads();
  int l16 = lane & 15, l4 = lane >> 4;
  const bf16* qbase = qf + (size_t)bh * S_SEQ * DHEAD;
  int q0w = mblk * 256 + w * 64;

  floatx4 acc[4][5] = {};
  bf16x8 af[4][2], bfr[5][2];
#pragma unroll
  for (int mt = 0; mt < 4; mt++) {
    int q = q0w + mt * 16 + l16;
    af[mt][0] = *(const bf16x8*)(qbase + (size_t)q * 64 + l4 * 8);
    af[mt][1] = *(const bf16x8*)(qbase + (size_t)q * 64 + 32 + l4 * 8);
  }
#pragma unroll
  for (int nt = 0; nt < 5; nt++) {
    bfr[nt][0] = *(const bf16x8*)&Bs[nt * 16 + l16][l4 * 8];
    bfr[nt][1] = *(const bf16x8*)&Bs[nt * 16 + l16][32 + l4 * 8];
  }
#pragma unroll
  for (int mt = 0; mt < 4; mt++)
#pragma unroll
    for (int nt = 0; nt < 5; nt++) {
      acc[mt][nt] = __builtin_amdgcn_mfma_f32_16x16x32_bf16(af[mt][0], bfr[nt][0], acc[mt][nt], 0, 0, 0);
      acc[mt][nt] = __builtin_amdgcn_mfma_f32_16x16x32_bf16(af[mt][1], bfr[nt][1], acc[mt][nt], 0, 0, 0);
    }
  // denominator: e=64 = col 0 of n-tile 4 (lanes with l16==0)
  if (l16 == 0) {
#pragma unroll
    for (int mt = 0; mt < 4; mt++)
#pragma unroll
      for (int r = 0; r < 4; r++)
        sden[w * 64 + mt * 16 + l4 * 4 + r] = acc[mt][4][r];
  }
  __syncthreads();
#pragma unroll
  for (int mt = 0; mt < 4; mt++)
#pragma unroll
    for (int r = 0; r < 4; r++) {
      float den = sden[w * 64 + mt * 16 + l4 * 4 + r] + LIN_EPS;
      float rden = 1.f / den;
      int q = q0w + mt * 16 + l4 * 4 + r;
#pragma unroll
      for (int nt = 0; nt < 4; nt++) {
        int dcol = nt * 16 + l16;
        float a = acc[mt][nt][r] * rden;
        if (q < L_SEQ)
          attn_x[((size_t)b * L_SEQ + q) * DMODEL + h * DHEAD + dcol] = (bf16)a;
        else
          attn_c[((size_t)b * C_SEQ + (q - L_SEQ)) * DMODEL + h * DHEAD + dcol] = (bf16)a;
      }
    }
}

// ---------------------------------------------------------------- final norm
// Reads bf16 y, writes FLOAT32 output (the reference's output dtype).
__global__ __launch_bounds__(256) void final_norm(
    const bf16* __restrict__ y_x, const bf16* __restrict__ y_c,
    const float* __restrict__ g_out, const float* __restrict__ cg_out,
    float* __restrict__ out) {
  int g = blockIdx.x, t = threadIdx.x;
  const bf16* src;
  const float* gv;
  if (g < NBATCH * L_SEQ) {
    src = y_x + (size_t)g * DMODEL; gv = g_out;
  } else {
    int gg = g - NBATCH * L_SEQ;
    src = y_c + (size_t)gg * DMODEL; gv = cg_out;
  }
  float* dst = out + (size_t)g * DMODEL;
  int d0 = t * 4;
  bf16x4 y4 = *(const bf16x4*)(src + d0);
  float yv[4], p = 0.f;
#pragma unroll
  for (int i = 0; i < 4; i++) { yv[i] = (float)y4[i]; p += yv[i] * yv[i]; }
  int lane = t & 63, w = t >> 6;
  for (int off = 32; off > 0; off >>= 1) p += __shfl_down(p, off, 64);
  __shared__ float red[4];
  if (lane == 0) red[w] = p;
  __syncthreads();
  float ssum = red[0] + red[1] + red[2] + red[3];
  float sc = rsqrtf(ssum * (1.f / DMODEL) + RMS_EPS);
  floatx4 o;
#pragma unroll
  for (int i = 0; i < 4; i++) o[i] = yv[i] * sc * gv[d0 + i];
  *(floatx4*)(dst + d0) = o;
}

// ---------------------------------------------------------------- launch
extern "C" void kernel_launch(void* const* d_in, const int* in_sizes, int n_in,
                              void* d_out, int out_size, void* d_ws, size_t ws_size,
                              hipStream_t stream) {
  const float* x      = (const float*)d_in[0];
  const float* ctx    = (const float*)d_in[1];
  const int*   mask   = (const int*)d_in[2];
  const int*   spos   = (const int*)d_in[3];
  const float* Wqkv   = (const float*)d_in[4];
  const float* bqkv   = (const float*)d_in[5];
  const float* g_q    = (const float*)d_in[6];
  const float* g_k    = (const float*)d_in[7];
  const float* cWqkv  = (const float*)d_in[8];
  const float* cbqkv  = (const float*)d_in[9];
  const float* cg_q   = (const float*)d_in[10];
  const float* cg_k   = (const float*)d_in[11];
  const float* Wout   = (const float*)d_in[12];
  const float* bout   = (const float*)d_in[13];
  const float* g_out  = (const float*)d_in[14];
  const float* cWout  = (const float*)d_in[15];
  const float* cbout  = (const float*)d_in[16];
  const float* cg_out = (const float*)d_in[17];

  char* wsp = (char*)d_ws;
  size_t off = 0;
  auto alloc = [&](size_t bytes) -> void* {
    void* p = wsp + off;
    off += (bytes + 255) & ~(size_t)255;
    return p;
  };
  bf16* WqkvT  = (bf16*)alloc((size_t)3072 * 1024 * 2);
  bf16* cWqkvT = (bf16*)alloc((size_t)3072 * 1024 * 2);
  bf16* WoutT  = (bf16*)alloc((size_t)1024 * 1024 * 2);
  bf16* cWoutT = (bf16*)alloc((size_t)1024 * 1024 * 2);
  bf16* xbf    = (bf16*)alloc((size_t)NBATCH * L_SEQ * DMODEL * 2);
  bf16* cbf    = (bf16*)alloc((size_t)NBATCH * C_SEQ * DMODEL * 2);
  const size_t SLAB = (size_t)NBATCH * NHEAD * S_SEQ * DHEAD;  // 9,437,184
  bf16* qfs    = (bf16*)alloc(SLAB * 2);
  bf16* kfs    = (bf16*)alloc(SLAB * 2);
  bf16* vfs    = (bf16*)alloc(SLAB * 2);   // holds vT [bh][d][s]
  float* vkw   = (float*)alloc((size_t)64 * 65 * 64 * 4);
  int* anym    = (int*)alloc(256);
  // attn aliases kf slab (dead after vk_mfma); y aliases v slab.
  bf16* attn_x = kfs;
  bf16* attn_c = kfs + (size_t)NBATCH * L_SEQ * DMODEL;
  bf16* y_x    = vfs;
  bf16* y_c    = vfs + (size_t)NBATCH * L_SEQ * DMODEL;

  // 1) weight transposes+convert (N x K bf16 for MFMA B-operand) + activation
  //    f32->bf16 converts (hoisted out of the GEMM to enable global_load_lds)
  transpose_f32_bf16<<<dim3(96, 32), 256, 0, stream>>>(Wqkv, WqkvT, 1024, 3072);
  transpose_f32_bf16<<<dim3(96, 32), 256, 0, stream>>>(cWqkv, cWqkvT, 1024, 3072);
  transpose_f32_bf16<<<dim3(32, 32), 256, 0, stream>>>(Wout, WoutT, 1024, 1024);
  transpose_f32_bf16<<<dim3(32, 32), 256, 0, stream>>>(cWout, cWoutT, 1024, 1024);
  convert_bf16<<<4096, 256, 0, stream>>>(x, xbf, (size_t)NBATCH * L_SEQ * DMODEL);
  convert_bf16<<<512, 256, 0, stream>>>(ctx, cbf, (size_t)NBATCH * C_SEQ * DMODEL);

  // 2) QKV projections -> head-major q/k slabs + transposed v slab
  gemm_bias<true><<<dim3(24, 64), 256, 0, stream>>>(
      xbf, WqkvT, bqkv, nullptr, qfs, kfs, vfs, 8192, 3072, 1024, 11, 0);
  gemm_bias<true><<<dim3(24, 8), 256, 0, stream>>>(
      cbf, cWqkvT, cbqkv, nullptr, qfs, kfs, vfs, 1024, 3072, 1024, 8, L_SEQ);

  // 3) mask helper + zero vk accumulator
  anymask_kernel<<<4, 256, 0, stream>>>(mask, anym);
  zero_f32<<<1040, 256, 0, stream>>>(vkw, 64 * 65 * 64);

  // 4) in-place rmsnorm + rope + relu + mask on q/k slabs
  qkv_post<<<NBATCH * (L_SEQ + C_SEQ), 256, 0, stream>>>(
      qfs, kfs, mask, spos, anym, g_q, g_k, cg_q, cg_k);

  // 5) vk = vT kf via MFMA
  vk_mfma<<<64 * VK_CH, 256, 0, stream>>>(vfs, kfs, vkw);

  // 6) res = qf vk^T, divide, scatter to token-major (B,S,D)
  res_attn<<<576, 256, 0, stream>>>(qfs, vkw, attn_x, attn_c);

  // 7) output projections
  gemm_bias<false><<<dim3(8, 64), 256, 0, stream>>>(
      attn_x, WoutT, bout, y_x, nullptr, nullptr, nullptr, 8192, 1024, 1024, 0, 0);
  gemm_bias<false><<<dim3(8, 8), 256, 0, stream>>>(
      attn_c, cWoutT, cbout, y_c, nullptr, nullptr, nullptr, 1024, 1024, 1024, 0, 0);

  // 8) final rmsnorm -> FLOAT32 d_out (x_out rows then c_out rows)
  final_norm<<<NBATCH * (L_SEQ + C_SEQ), 256, 0, stream>>>(
      y_x, y_c, g_out, cg_out, (float*)d_out);
}

// Round 3
// 356.635 us; speedup vs baseline: 1.5209x; 1.1519x over previous
//
#include <hip/hip_runtime.h>

typedef __bf16 bf16;
typedef __bf16 bf16x4 __attribute__((ext_vector_type(4)));
typedef __bf16 bf16x8 __attribute__((ext_vector_type(8)));
typedef float  floatx4 __attribute__((ext_vector_type(4)));

#define L_SEQ   2048
#define C_SEQ   256
#define S_SEQ   2304
#define NBATCH  4
#define NHEAD   16
#define DHEAD   64
#define DMODEL  1024
#define RMS_EPS 1.1920928955078125e-07f
#define LIN_EPS 1e-6f

// async global->LDS, 16B per lane; LDS dest must be wave-uniform (+lane*16)
__device__ __forceinline__ void gload_lds16(const void* g, void* l) {
  __builtin_amdgcn_global_load_lds(
      (const __attribute__((address_space(1))) void*)g,
      (__attribute__((address_space(3))) void*)l, 16, 0, 0);
}

// ---------------------------------------------------------------- prep jobs
__device__ __forceinline__ void transpose_job(
    const float* __restrict__ src, bf16* __restrict__ dst,
    int R, int C, int tb, bf16 (*tile)[33]) {
  int tilesx = C >> 5;
  int c0 = (tb % tilesx) * 32, r0 = (tb / tilesx) * 32;
  int tx = threadIdx.x & 31, ty = threadIdx.x >> 5;
  for (int i = ty; i < 32; i += 8)
    tile[i][tx] = (bf16)src[(size_t)(r0 + i) * C + c0 + tx];
  __syncthreads();
  for (int i = ty; i < 32; i += 8)
    dst[(size_t)(c0 + i) * R + r0 + tx] = tile[tx][i];
}

__device__ __forceinline__ void convert_job(
    const float* __restrict__ src, bf16* __restrict__ dst, int tb) {
  size_t i = ((size_t)tb * 256 + threadIdx.x) * 8;
  floatx4 a = *(const floatx4*)(src + i);
  floatx4 b = *(const floatx4*)(src + i + 4);
  bf16x8 o;
#pragma unroll
  for (int j = 0; j < 4; j++) { o[j] = (bf16)a[j]; o[4 + j] = (bf16)b[j]; }
  *(bf16x8*)(dst + i) = o;
}

// One fused kernel for all independent prep work:
//   [0,3072)      Wqkv transpose   (1024x3072)
//   [3072,6144)   cWqkv transpose
//   [6144,7168)   Wout transpose   (1024x1024)
//   [7168,8192)   cWout transpose
//   [8192,12288)  x   f32->bf16    (8M elems)
//   [12288,12800) ctx f32->bf16    (1M elems)
//   [12800,13060) zero vkw         (266240 f32)
//   [13060,13064) anymask          (4 batches)
__global__ __launch_bounds__(256) void prep(
    const float* __restrict__ Wqkv, const float* __restrict__ cWqkv,
    const float* __restrict__ Wout, const float* __restrict__ cWout,
    const float* __restrict__ x, const float* __restrict__ ctx,
    const int* __restrict__ mask,
    bf16* __restrict__ WqkvT, bf16* __restrict__ cWqkvT,
    bf16* __restrict__ WoutT, bf16* __restrict__ cWoutT,
    bf16* __restrict__ xbf, bf16* __restrict__ cbf,
    float* __restrict__ vkw, int* __restrict__ anym) {
  __shared__ bf16 tile[32][33];
  __shared__ int sh;
  int b = blockIdx.x;
  if (b < 3072) { transpose_job(Wqkv, WqkvT, 1024, 3072, b, tile); return; }
  b -= 3072;
  if (b < 3072) { transpose_job(cWqkv, cWqkvT, 1024, 3072, b, tile); return; }
  b -= 3072;
  if (b < 1024) { transpose_job(Wout, WoutT, 1024, 1024, b, tile); return; }
  b -= 1024;
  if (b < 1024) { transpose_job(cWout, cWoutT, 1024, 1024, b, tile); return; }
  b -= 1024;
  if (b < 4096) { convert_job(x, xbf, b); return; }
  b -= 4096;
  if (b < 512) { convert_job(ctx, cbf, b); return; }
  b -= 512;
  if (b < 260) {
    int i = b * 1024 + threadIdx.x * 4;
    *(floatx4*)(vkw + i) = floatx4{0.f, 0.f, 0.f, 0.f};
    return;
  }
  b -= 260;
  // anymask: any(mask[b][0][:])
  int a = 0;
  size_t base = (size_t)b * L_SEQ * L_SEQ;
  for (int j = threadIdx.x; j < L_SEQ; j += 256) a |= mask[base + j];
  if (threadIdx.x == 0) sh = 0;
  __syncthreads();
  if (a) atomicOr(&sh, 1);
  __syncthreads();
  if (threadIdx.x == 0) anym[b] = sh;
}

// ---------------------------------------------------------------- GEMM
// Combined pair launch: grid.y < ybound -> part 1 (A1/B1t/bias1), else part 2.
// 2-phase double-buffered global_load_lds staging (one barrier per K-step),
// XCD-aware block swizzle, 128x128 tile BK=32, 4 waves, 4x4 mfma_16x16x32.
// SCATTER: col -> (which={q,k,v}, h, dh); q/k head-major [bh][s][dh],
// v TRANSPOSED [bh][dh][s] (bf16x4 store along s).
template <bool SCATTER>
__global__ __launch_bounds__(256) void gemm_bias(
    const bf16* __restrict__ A1, const bf16* __restrict__ A2,
    const bf16* __restrict__ B1t, const bf16* __restrict__ B2t,
    const float* __restrict__ bias1, const float* __restrict__ bias2,
    bf16* __restrict__ C1, bf16* __restrict__ C2,
    bf16* __restrict__ qs, bf16* __restrict__ ks, bf16* __restrict__ vs,
    int N, int K, int ybound,
    int rpb1, int soff1, int rpb2, int soff2) {
  __shared__ bf16 As[2][4096];   // [buf][128*32] linear, 64B rows
  __shared__ bf16 Bs[2][4096];

  // XCD-aware swizzle (bijective: nwg % 8 == 0 for all our grids)
  int nwg = gridDim.x * gridDim.y;
  int wg = blockIdx.y * gridDim.x + blockIdx.x;
  if ((nwg & 7) == 0) {
    int cpx = nwg >> 3;
    wg = (wg & 7) * cpx + (wg >> 3);
  }
  int bx = wg % gridDim.x, by = wg / gridDim.x;
  int n0 = bx * 128;
  const bf16 *Ap, *Bt;
  const float* bias;
  bf16* Cp;
  int m0, rpb, soff;
  if (by < ybound) {
    Ap = A1; Bt = B1t; bias = bias1; Cp = C1;
    m0 = by * 128; rpb = rpb1; soff = soff1;
  } else {
    Ap = A2; Bt = B2t; bias = bias2; Cp = C2;
    m0 = (by - ybound) * 128; rpb = rpb2; soff = soff2;
  }

  int t = threadIdx.x;
  int lane = t & 63, w = t >> 6;
  int wm = (w & 1) * 64, wn = (w >> 1) * 64;
  int l16 = lane & 15, l4 = lane >> 4;

  // staging: chunk c=w*2+j covers rows [c*16,c*16+16); lane l -> row c*16+l/4,
  // col (l&3)*8 (16B). LDS dest wave-uniform base + lane*16.
  int srow = w * 32 + (lane >> 2);
  int scol = (lane & 3) * 8;
  const bf16* Ab = Ap + (size_t)(m0 + srow) * K + scol;
  const bf16* Bb = Bt + (size_t)(n0 + srow) * K + scol;

  auto stage = [&](int buf, int kb) {
#pragma unroll
    for (int j = 0; j < 2; j++) {
      gload_lds16(Ab + (size_t)j * 16 * K + kb, (char*)&As[buf][(w * 2 + j) * 512]);
      gload_lds16(Bb + (size_t)j * 16 * K + kb, (char*)&Bs[buf][(w * 2 + j) * 512]);
    }
  };

  floatx4 acc[4][4] = {};
  stage(0, 0);
  __syncthreads();
  int cur = 0;
  for (int kb = 0; kb < K; kb += 32) {
    if (kb + 32 < K) stage(cur ^ 1, kb + 32);   // prefetch overlaps compute
    bf16x8 af[4], bfr[4];
#pragma unroll
    for (int i = 0; i < 4; i++) {
      af[i]  = *(const bf16x8*)&As[cur][(wm + i * 16 + l16) * 32 + l4 * 8];
      bfr[i] = *(const bf16x8*)&Bs[cur][(wn + i * 16 + l16) * 32 + l4 * 8];
    }
#pragma unroll
    for (int i = 0; i < 4; i++)
#pragma unroll
      for (int j = 0; j < 4; j++)
        acc[i][j] = __builtin_amdgcn_mfma_f32_16x16x32_bf16(af[i], bfr[j], acc[i][j], 0, 0, 0);
    __syncthreads();               // drains prefetch vmcnt + protects reads
    cur ^= 1;
  }
  // epilogue: D[row=(l>>4)*4+r][col=l&15] per 16x16 tile
#pragma unroll
  for (int i = 0; i < 4; i++)
#pragma unroll
    for (int j = 0; j < 4; j++) {
      int col = n0 + wn + j * 16 + l16;
      float bval = bias[col];
      if constexpr (SCATTER) {
        int which = col >> 10;
        int h = (col >> 6) & 15;
        int dh = col & 63;
        int rmask = (1 << rpb) - 1;
        if (which == 2) {
          int rw0 = m0 + wm + i * 16 + l4 * 4;
          int b = rw0 >> rpb;
          int s = soff + (rw0 & rmask);
          bf16x4 o;
#pragma unroll
          for (int r = 0; r < 4; r++) o[r] = (bf16)(acc[i][j][r] + bval);
          *(bf16x4*)(vs + ((size_t)(b * NHEAD + h) * DHEAD + dh) * S_SEQ + s) = o;
        } else {
          bf16* dst = which == 0 ? qs : ks;
#pragma unroll
          for (int r = 0; r < 4; r++) {
            int rw = m0 + wm + i * 16 + l4 * 4 + r;
            int b = rw >> rpb;
            int s = soff + (rw & rmask);
            dst[((size_t)(b * NHEAD + h) * S_SEQ + s) * DHEAD + dh] =
                (bf16)(acc[i][j][r] + bval);
          }
        }
      } else {
#pragma unroll
        for (int r = 0; r < 4; r++) {
          int rw = m0 + wm + i * 16 + l4 * 4 + r;
          Cp[(size_t)rw * N + col] = (bf16)(acc[i][j][r] + bval);
        }
      }
    }
}

// ---------------------------------------------------------------- qkv post
// One block per token (9216). In-place on head-major q/k slabs: rmsnorm over
// D=1024, RoPE (x tokens only), relu; key-mask on k.
__global__ __launch_bounds__(256) void qkv_post(
    bf16* __restrict__ qs, bf16* __restrict__ ks,
    const int* __restrict__ mask, const int* __restrict__ spos,
    const int* __restrict__ anym,
    const float* __restrict__ g_q, const float* __restrict__ g_k,
    const float* __restrict__ cg_q, const float* __restrict__ cg_k) {
  int g = blockIdx.x, t = threadIdx.x;
  bool is_ctx = g >= NBATCH * L_SEQ;
  int b, s;
  const float *gq, *gk;
  float mval;
  if (!is_ctx) {
    b = g >> 11;
    int l = g & 2047;
    s = l;
    mval = mask[(size_t)b * L_SEQ * L_SEQ + l] ? 1.f : 0.f;  // mask[b][0][l]
    gq = g_q; gk = g_k;
  } else {
    int gg = g - NBATCH * L_SEQ;
    b = gg >> 8;
    s = L_SEQ + (gg & 255);
    mval = anym[b] ? 1.f : 0.f;
    gq = cg_q; gk = cg_k;
  }
  int d0 = t * 4;
  int h = t >> 4, dh = (t & 15) * 4;            // h*64+dh == d0
  size_t base = ((size_t)(b * NHEAD + h) * S_SEQ + s) * DHEAD + dh;
  bf16x4 q4 = *(const bf16x4*)(qs + base);
  bf16x4 k4 = *(const bf16x4*)(ks + base);
  float qv[4], kv[4], pq = 0.f, pk = 0.f;
#pragma unroll
  for (int i = 0; i < 4; i++) {
    qv[i] = (float)q4[i]; kv[i] = (float)k4[i];
    pq += qv[i] * qv[i];  pk += kv[i] * kv[i];
  }
  int lane = t & 63, w = t >> 6;
  for (int off = 32; off > 0; off >>= 1) {
    pq += __shfl_down(pq, off, 64);
    pk += __shfl_down(pk, off, 64);
  }
  __shared__ float red[8];
  if (lane == 0) { red[w] = pq; red[4 + w] = pk; }
  __syncthreads();
  float sq = red[0] + red[1] + red[2] + red[3];
  float sk = red[4] + red[5] + red[6] + red[7];
  float scq = rsqrtf(sq * (1.f / DMODEL) + RMS_EPS);
  float sck = rsqrtf(sk * (1.f / DMODEL) + RMS_EPS);
#pragma unroll
  for (int i = 0; i < 4; i++) {
    qv[i] *= scq * gq[d0 + i];
    kv[i] *= sck * gk[d0 + i];
  }
  if (!is_ctx) {
    float p = (float)(spos[b] + s);
#pragma unroll
    for (int pr = 0; pr < 2; pr++) {
      int fi = (dh >> 1) + pr;                              // freq 0..31
      float ang = p * expf((float)fi * -0.28782313662425572f);  // ln(1e4)/32
      float cc = cosf(ang), ss = sinf(ang);
      float t0 = qv[2 * pr], t1 = qv[2 * pr + 1];
      qv[2 * pr]     = t0 * cc - t1 * ss;
      qv[2 * pr + 1] = t0 * ss + t1 * cc;
      t0 = kv[2 * pr]; t1 = kv[2 * pr + 1];
      kv[2 * pr]     = t0 * cc - t1 * ss;
      kv[2 * pr + 1] = t0 * ss + t1 * cc;
    }
  }
  bf16x4 qo, ko;
#pragma unroll
  for (int i = 0; i < 4; i++) {
    qo[i] = (bf16)fmaxf(qv[i], 0.f);
    ko[i] = (bf16)(fmaxf(kv[i], 0.f) * mval);
  }
  *(bf16x4*)(qs + base) = qo;
  *(bf16x4*)(ks + base) = ko;
}

// ---------------------------------------------------------------- vk (MFMA)
// vk[bh][e][d] = sum_s vT[bh][e][s] * kf[bh][s][d]; row e=64: sum_s kf[s][d].
// 1-barrier reg-staged double-buffer: write LDS[cur] from regs, issue next
// tile's global loads, barrier, compute. Partials atomicAdd into zeroed vkw.
#define VK_CH   8
#define VK_SPAN (S_SEQ / VK_CH)   // 288 = 9 K-steps of 32
__global__ __launch_bounds__(256) void vk_mfma(
    const bf16* __restrict__ vT, const bf16* __restrict__ kf,
    float* __restrict__ vk) {
  __shared__ bf16 Vs[2][64][40];
  __shared__ bf16 Ks[2][64][40];   // Ks[d][s]
  int bh = blockIdx.x >> 3, chunk = blockIdx.x & 7;
  int t = threadIdx.x, lane = t & 63, w = t >> 6;
  int l16 = lane & 15, l4 = lane >> 4;
  const bf16* vp = vT + (size_t)bh * DHEAD * S_SEQ;
  const bf16* kp = kf + (size_t)bh * S_SEQ * DHEAD;
  int s_begin = chunk * VK_SPAN;
  int ve = t >> 2, vso = (t & 3) * 8;        // v staging: row e, col offset
  int ks_s = t & 31, kd0 = (t >> 5) * 8;     // kf staging: s-slice, d-octet
  floatx4 acc[4] = {};
  float dsum[8] = {};
  bf16x8 vv = *(const bf16x8*)(vp + (size_t)ve * S_SEQ + s_begin + vso);
  bf16x8 kv = *(const bf16x8*)(kp + (size_t)(s_begin + ks_s) * DHEAD + kd0);
  for (int st = 0; st < VK_SPAN; st += 32) {
    int cur = (st >> 5) & 1;
    *(bf16x8*)&Vs[cur][ve][vso] = vv;
#pragma unroll
    for (int j = 0; j < 8; j++) {
      Ks[cur][kd0 + j][ks_s] = kv[j];
      dsum[j] += (float)kv[j];
    }
    if (st + 32 < VK_SPAN) {
      int s0 = s_begin + st + 32;
      vv = *(const bf16x8*)(vp + (size_t)ve * S_SEQ + s0 + vso);
      kv = *(const bf16x8*)(kp + (size_t)(s0 + ks_s) * DHEAD + kd0);
    }
    __syncthreads();
    bf16x8 af = *(const bf16x8*)&Vs[cur][w * 16 + l16][l4 * 8];
#pragma unroll
    for (int nt = 0; nt < 4; nt++) {
      bf16x8 bfr = *(const bf16x8*)&Ks[cur][nt * 16 + l16][l4 * 8];
      acc[nt] = __builtin_amdgcn_mfma_f32_16x16x32_bf16(af, bfr, acc[nt], 0, 0, 0);
    }
  }
  float* vkbh = vk + (size_t)bh * 65 * 64;
#pragma unroll
  for (int nt = 0; nt < 4; nt++)
#pragma unroll
    for (int r = 0; r < 4; r++)
      atomicAdd(&vkbh[(w * 16 + l4 * 4 + r) * 64 + nt * 16 + l16], acc[nt][r]);
#pragma unroll
  for (int j = 0; j < 8; j++)
#pragma unroll
    for (int off = 16; off > 0; off >>= 1)
      dsum[j] += __shfl_down(dsum[j], off, 32);
  if ((lane & 31) == 0)
#pragma unroll
    for (int j = 0; j < 8; j++)
      atomicAdd(&vkbh[64 * 64 + kd0 + j], dsum[j]);
}

// ---------------------------------------------------------------- res + div
// res[q][e] = sum_d qf[q][d]*vk[e][d]; attn = res[:,:64]/(res[:,64]+eps).
__global__ __launch_bounds__(256) void res_attn(
    const bf16* __restrict__ qf, const float* __restrict__ vk,
    bf16* __restrict__ attn_x, bf16* __restrict__ attn_c) {
  __shared__ bf16 Bs[80][72];
  __shared__ float sden[256];
  int bh = blockIdx.x / 9, mblk = blockIdx.x % 9;
  int b = bh >> 4, h = bh & 15;
  int t = threadIdx.x, lane = t & 63, w = t >> 6;
  const float* vkp = vk + (size_t)bh * 65 * 64;
  for (int i = t; i < 80 * 64; i += 256) {
    int e = i >> 6, d = i & 63;
    Bs[e][d] = (bf16)(e < 65 ? vkp[i] : 0.f);
  }
  __syncthreads();
  int l16 = lane & 15, l4 = lane >> 4;
  const bf16* qbase = qf + (size_t)bh * S_SEQ * DHEAD;
  int q0w = mblk * 256 + w * 64;

  floatx4 acc[4][5] = {};
  bf16x8 af[4][2], bfr[5][2];
#pragma unroll
  for (int mt = 0; mt < 4; mt++) {
    int q = q0w + mt * 16 + l16;
    af[mt][0] = *(const bf16x8*)(qbase + (size_t)q * 64 + l4 * 8);
    af[mt][1] = *(const bf16x8*)(qbase + (size_t)q * 64 + 32 + l4 * 8);
  }
#pragma unroll
  for (int nt = 0; nt < 5; nt++) {
    bfr[nt][0] = *(const bf16x8*)&Bs[nt * 16 + l16][l4 * 8];
    bfr[nt][1] = *(const bf16x8*)&Bs[nt * 16 + l16][32 + l4 * 8];
  }
#pragma unroll
  for (int mt = 0; mt < 4; mt++)
#pragma unroll
    for (int nt = 0; nt < 5; nt++) {
      acc[mt][nt] = __builtin_amdgcn_mfma_f32_16x16x32_bf16(af[mt][0], bfr[nt][0], acc[mt][nt], 0, 0, 0);
      acc[mt][nt] = __builtin_amdgcn_mfma_f32_16x16x32_bf16(af[mt][1], bfr[nt][1], acc[mt][nt], 0, 0, 0);
    }
  // denominator: e=64 = col 0 of n-tile 4 (lanes with l16==0)
  if (l16 == 0) {
#pragma unroll
    for (int mt = 0; mt < 4; mt++)
#pragma unroll
      for (int r = 0; r < 4; r++)
        sden[w * 64 + mt * 16 + l4 * 4 + r] = acc[mt][4][r];
  }
  __syncthreads();
#pragma unroll
  for (int mt = 0; mt < 4; mt++)
#pragma unroll
    for (int r = 0; r < 4; r++) {
      float den = sden[w * 64 + mt * 16 + l4 * 4 + r] + LIN_EPS;
      float rden = 1.f / den;
      int q = q0w + mt * 16 + l4 * 4 + r;
#pragma unroll
      for (int nt = 0; nt < 4; nt++) {
        int dcol = nt * 16 + l16;
        float a = acc[mt][nt][r] * rden;
        if (q < L_SEQ)
          attn_x[((size_t)b * L_SEQ + q) * DMODEL + h * DHEAD + dcol] = (bf16)a;
        else
          attn_c[((size_t)b * C_SEQ + (q - L_SEQ)) * DMODEL + h * DHEAD + dcol] = (bf16)a;
      }
    }
}

// ---------------------------------------------------------------- final norm
// Reads bf16 y, writes FLOAT32 output (the reference's output dtype).
__global__ __launch_bounds__(256) void final_norm(
    const bf16* __restrict__ y_x, const bf16* __restrict__ y_c,
    const float* __restrict__ g_out, const float* __restrict__ cg_out,
    float* __restrict__ out) {
  int g = blockIdx.x, t = threadIdx.x;
  const bf16* src;
  const float* gv;
  if (g < NBATCH * L_SEQ) {
    src = y_x + (size_t)g * DMODEL; gv = g_out;
  } else {
    int gg = g - NBATCH * L_SEQ;
    src = y_c + (size_t)gg * DMODEL; gv = cg_out;
  }
  float* dst = out + (size_t)g * DMODEL;
  int d0 = t * 4;
  bf16x4 y4 = *(const bf16x4*)(src + d0);
  float yv[4], p = 0.f;
#pragma unroll
  for (int i = 0; i < 4; i++) { yv[i] = (float)y4[i]; p += yv[i] * yv[i]; }
  int lane = t & 63, w = t >> 6;
  for (int off = 32; off > 0; off >>= 1) p += __shfl_down(p, off, 64);
  __shared__ float red[4];
  if (lane == 0) red[w] = p;
  __syncthreads();
  float ssum = red[0] + red[1] + red[2] + red[3];
  float sc = rsqrtf(ssum * (1.f / DMODEL) + RMS_EPS);
  floatx4 o;
#pragma unroll
  for (int i = 0; i < 4; i++) o[i] = yv[i] * sc * gv[d0 + i];
  *(floatx4*)(dst + d0) = o;
}

// ---------------------------------------------------------------- launch
extern "C" void kernel_launch(void* const* d_in, const int* in_sizes, int n_in,
                              void* d_out, int out_size, void* d_ws, size_t ws_size,
                              hipStream_t stream) {
  const float* x      = (const float*)d_in[0];
  const float* ctx    = (const float*)d_in[1];
  const int*   mask   = (const int*)d_in[2];
  const int*   spos   = (const int*)d_in[3];
  const float* Wqkv   = (const float*)d_in[4];
  const float* bqkv   = (const float*)d_in[5];
  const float* g_q    = (const float*)d_in[6];
  const float* g_k    = (const float*)d_in[7];
  const float* cWqkv  = (const float*)d_in[8];
  const float* cbqkv  = (const float*)d_in[9];
  const float* cg_q   = (const float*)d_in[10];
  const float* cg_k   = (const float*)d_in[11];
  const float* Wout   = (const float*)d_in[12];
  const float* bout   = (const float*)d_in[13];
  const float* g_out  = (const float*)d_in[14];
  const float* cWout  = (const float*)d_in[15];
  const float* cbout  = (const float*)d_in[16];
  const float* cg_out = (const float*)d_in[17];

  char* wsp = (char*)d_ws;
  size_t off = 0;
  auto alloc = [&](size_t bytes) -> void* {
    void* p = wsp + off;
    off += (bytes + 255) & ~(size_t)255;
    return p;
  };
  bf16* WqkvT  = (bf16*)alloc((size_t)3072 * 1024 * 2);
  bf16* cWqkvT = (bf16*)alloc((size_t)3072 * 1024 * 2);
  bf16* WoutT  = (bf16*)alloc((size_t)1024 * 1024 * 2);
  bf16* cWoutT = (bf16*)alloc((size_t)1024 * 1024 * 2);
  bf16* xbf    = (bf16*)alloc((size_t)NBATCH * L_SEQ * DMODEL * 2);
  bf16* cbf    = (bf16*)alloc((size_t)NBATCH * C_SEQ * DMODEL * 2);
  const size_t SLAB = (size_t)NBATCH * NHEAD * S_SEQ * DHEAD;  // 9,437,184
  bf16* qfs    = (bf16*)alloc(SLAB * 2);
  bf16* kfs    = (bf16*)alloc(SLAB * 2);
  bf16* vfs    = (bf16*)alloc(SLAB * 2);   // holds vT [bh][d][s]
  float* vkw   = (float*)alloc((size_t)64 * 65 * 64 * 4);
  int* anym    = (int*)alloc(256);
  // attn aliases kf slab (dead after vk_mfma); y aliases v slab.
  bf16* attn_x = kfs;
  bf16* attn_c = kfs + (size_t)NBATCH * L_SEQ * DMODEL;
  bf16* y_x    = vfs;
  bf16* y_c    = vfs + (size_t)NBATCH * L_SEQ * DMODEL;

  // 1) fused prep: weight transposes, activation converts, vkw zero, anymask
  prep<<<13064, 256, 0, stream>>>(Wqkv, cWqkv, Wout, cWout, x, ctx, mask,
                                  WqkvT, cWqkvT, WoutT, cWoutT, xbf, cbf,
                                  vkw, anym);

  // 2) QKV projections (x + ctx in one launch) -> head-major q/k + vT slabs
  gemm_bias<true><<<dim3(24, 72), 256, 0, stream>>>(
      xbf, cbf, WqkvT, cWqkvT, bqkv, cbqkv, nullptr, nullptr,
      qfs, kfs, vfs, 3072, 1024, 64, 11, 0, 8, L_SEQ);

  // 3) in-place rmsnorm + rope + relu + mask on q/k slabs
  qkv_post<<<NBATCH * (L_SEQ + C_SEQ), 256, 0, stream>>>(
      qfs, kfs, mask, spos, anym, g_q, g_k, cg_q, cg_k);

  // 4) vk = vT kf via MFMA
  vk_mfma<<<64 * VK_CH, 256, 0, stream>>>(vfs, kfs, vkw);

  // 5) res = qf vk^T, divide, scatter to token-major (B,S,D)
  res_attn<<<576, 256, 0, stream>>>(qfs, vkw, attn_x, attn_c);

  // 6) output projections (x + ctx in one launch)
  gemm_bias<false><<<dim3(8, 72), 256, 0, stream>>>(
      attn_x, attn_c, WoutT, cWoutT, bout, cbout, y_x, y_c,
      nullptr, nullptr, nullptr, 1024, 1024, 64, 0, 0, 0, 0);

  // 7) final rmsnorm -> FLOAT32 d_out (x_out rows then c_out rows)
  final_norm<<<NBATCH * (L_SEQ + C_SEQ), 256, 0, stream>>>(
      y_x, y_c, g_out, cg_out, (float*)d_out);
}

// Round 4
// 350.342 us; speedup vs baseline: 1.5482x; 1.0180x over previous
//
#include <hip/hip_runtime.h>

typedef __bf16 bf16;
typedef __bf16 bf16x4 __attribute__((ext_vector_type(4)));
typedef __bf16 bf16x8 __attribute__((ext_vector_type(8)));
typedef float  floatx4 __attribute__((ext_vector_type(4)));

#define L_SEQ   2048
#define C_SEQ   256
#define S_SEQ   2304
#define NBATCH  4
#define NHEAD   16
#define DHEAD   64
#define DMODEL  1024
#define RMS_EPS 1.1920928955078125e-07f
#define LIN_EPS 1e-6f

// async global->LDS, 16B per lane; LDS dest must be wave-uniform (+lane*16)
__device__ __forceinline__ void gload_lds16(const void* g, void* l) {
  __builtin_amdgcn_global_load_lds(
      (const __attribute__((address_space(1))) void*)g,
      (__attribute__((address_space(3))) void*)l, 16, 0, 0);
}

// ---------------------------------------------------------------- prep jobs
__device__ __forceinline__ void transpose_job(
    const float* __restrict__ src, bf16* __restrict__ dst,
    int R, int C, int tb, bf16 (*tile)[33]) {
  int tilesx = C >> 5;
  int c0 = (tb % tilesx) * 32, r0 = (tb / tilesx) * 32;
  int tx = threadIdx.x & 31, ty = threadIdx.x >> 5;
  for (int i = ty; i < 32; i += 8)
    tile[i][tx] = (bf16)src[(size_t)(r0 + i) * C + c0 + tx];
  __syncthreads();
  for (int i = ty; i < 32; i += 8)
    dst[(size_t)(c0 + i) * R + r0 + tx] = tile[tx][i];
}

__device__ __forceinline__ void convert_job(
    const float* __restrict__ src, bf16* __restrict__ dst, int tb) {
  size_t i = ((size_t)tb * 256 + threadIdx.x) * 8;
  floatx4 a = *(const floatx4*)(src + i);
  floatx4 b = *(const floatx4*)(src + i + 4);
  bf16x8 o;
#pragma unroll
  for (int j = 0; j < 4; j++) { o[j] = (bf16)a[j]; o[4 + j] = (bf16)b[j]; }
  *(bf16x8*)(dst + i) = o;
}

// One fused kernel for all independent prep work:
//   [0,3072)        Wqkv transpose   (1024x3072)
//   [3072,6144)     cWqkv transpose
//   [6144,7168)     Wout transpose   (1024x1024)
//   [7168,8192)     cWout transpose
//   [8192,12288)    x   f32->bf16    (8M elems)
//   [12288,12800)   ctx f32->bf16    (1M elems)
//   [12800,13060)   zero vkw         (266240 f32)
//   [13060,15108)   rope cos/sin table (8192 tokens x 32 freqs x {c,s})
//   [15108,15112)   anymask          (4 batches)
__global__ __launch_bounds__(256) void prep(
    const float* __restrict__ Wqkv, const float* __restrict__ cWqkv,
    const float* __restrict__ Wout, const float* __restrict__ cWout,
    const float* __restrict__ x, const float* __restrict__ ctx,
    const int* __restrict__ mask, const int* __restrict__ spos,
    bf16* __restrict__ WqkvT, bf16* __restrict__ cWqkvT,
    bf16* __restrict__ WoutT, bf16* __restrict__ cWoutT,
    bf16* __restrict__ xbf, bf16* __restrict__ cbf,
    float* __restrict__ vkw, float* __restrict__ rope,
    int* __restrict__ anym) {
  __shared__ bf16 tile[32][33];
  __shared__ int sh;
  int b = blockIdx.x;
  if (b < 3072) { transpose_job(Wqkv, WqkvT, 1024, 3072, b, tile); return; }
  b -= 3072;
  if (b < 3072) { transpose_job(cWqkv, cWqkvT, 1024, 3072, b, tile); return; }
  b -= 3072;
  if (b < 1024) { transpose_job(Wout, WoutT, 1024, 1024, b, tile); return; }
  b -= 1024;
  if (b < 1024) { transpose_job(cWout, cWoutT, 1024, 1024, b, tile); return; }
  b -= 1024;
  if (b < 4096) { convert_job(x, xbf, b); return; }
  b -= 4096;
  if (b < 512) { convert_job(ctx, cbf, b); return; }
  b -= 512;
  if (b < 260) {
    int i = b * 1024 + threadIdx.x * 4;
    *(floatx4*)(vkw + i) = floatx4{0.f, 0.f, 0.f, 0.f};
    return;
  }
  b -= 260;
  if (b < 2048) {
    // rope table: token = b*4 + t/64 (x tokens only), j = t&63, fi = j>>1
    int t = threadIdx.x;
    int tok = b * 4 + (t >> 6);
    int bb = tok >> 11, s = tok & 2047;
    int j = t & 63, fi = j >> 1;
    float ang = (float)(spos[bb] + s) * expf((float)fi * -0.28782313662425572f);
    rope[(size_t)tok * 64 + j] = (j & 1) ? sinf(ang) : cosf(ang);
    return;
  }
  b -= 2048;
  // anymask: any(mask[b][0][:])
  int a = 0;
  size_t base = (size_t)b * L_SEQ * L_SEQ;
  for (int j = threadIdx.x; j < L_SEQ; j += 256) a |= mask[base + j];
  if (threadIdx.x == 0) sh = 0;
  __syncthreads();
  if (a) atomicOr(&sh, 1);
  __syncthreads();
  if (threadIdx.x == 0) anym[b] = sh;
}

// ---------------------------------------------------------------- GEMM
// 256x256 tile, BK=64, 8 waves (2M x 4N), 128 KiB double-buffered LDS.
// Schedule: no intra-tile barriers (stage writes only the other buffer);
// tile t's compute covers tile t+1's 8 global_load_lds; one __syncthreads
// (vmcnt drain) per K-tile. T2 bank swizzle: logical (row,c) stored at
// byte c ^ ((row&7)<<4) via pre-swizzled GLOBAL source (gload_lds dest is
// linear) + swizzled ds_read. T5 setprio around the MFMA cluster.
// Pair launch: by < ybound -> part 1, else part 2. SCATTER as before.
template <bool SCATTER>
__global__ __launch_bounds__(512, 2) void gemm_bias(
    const bf16* __restrict__ A1, const bf16* __restrict__ A2,
    const bf16* __restrict__ B1t, const bf16* __restrict__ B2t,
    const float* __restrict__ bias1, const float* __restrict__ bias2,
    bf16* __restrict__ C1, bf16* __restrict__ C2,
    bf16* __restrict__ qs, bf16* __restrict__ ks, bf16* __restrict__ vs,
    int N, int K, int ybound,
    int rpb1, int soff1, int rpb2, int soff2) {
  __shared__ bf16 As[2][16384];   // [buf][256 rows x 64 cols]
  __shared__ bf16 Bs[2][16384];

  // XCD-aware swizzle (all grids have nwg % 8 == 0)
  int nwg = gridDim.x * gridDim.y;
  int wg = blockIdx.y * gridDim.x + blockIdx.x;
  int cpx = nwg >> 3;
  wg = (wg & 7) * cpx + (wg >> 3);
  int bx = wg % gridDim.x, by = wg / gridDim.x;
  int n0 = bx * 256;
  const bf16 *Ap, *Bt;
  const float* bias;
  bf16* Cp;
  int m0, rpb, soff;
  if (by < ybound) {
    Ap = A1; Bt = B1t; bias = bias1; Cp = C1;
    m0 = by * 256; rpb = rpb1; soff = soff1;
  } else {
    Ap = A2; Bt = B2t; bias = bias2; Cp = C2;
    m0 = (by - ybound) * 256; rpb = rpb2; soff = soff2;
  }

  int t = threadIdx.x, lane = t & 63, w = t >> 6;
  int wr = w >> 2, wc = w & 3;           // wave tile: rows wr*128, cols wc*64
  int l16 = lane & 15, l4 = lane >> 4;

  // staging: wave w instr j covers LDS rows [w*32+j*8, +8) linearly; lane l
  // -> row w*32+j*8+(l>>3), linear col-byte (l&7)*16. Global source column
  // pre-swizzled: elem = ((l&7)^(l>>3))*8  (involution of the read swizzle).
  int srow = w * 32 + (lane >> 3);
  int scol = ((lane & 7) ^ (lane >> 3)) << 3;
  const bf16* Ab = Ap + (size_t)(m0 + srow) * K + scol;
  const bf16* Bb = Bt + (size_t)(n0 + srow) * K + scol;

  // ds_read swizzled col offsets (elements): (kk*32 + l4*8) ^ ((l16&7)<<3)
  int co0 = (l4 * 8) ^ ((l16 & 7) << 3);
  int co1 = (32 + l4 * 8) ^ ((l16 & 7) << 3);
  int rba = (wr * 128 + l16) * 64;
  int rbb = (wc * 64 + l16) * 64;

  floatx4 acc[8][4] = {};

  // prologue: stage tile 0 -> buf 0
#pragma unroll
  for (int j = 0; j < 4; j++) {
    gload_lds16(Ab + (size_t)j * 8 * K, (char*)As + w * 4096 + j * 1024);
    gload_lds16(Bb + (size_t)j * 8 * K, (char*)Bs + w * 4096 + j * 1024);
  }
  __syncthreads();

  int NT = K >> 6;
  for (int tt = 0; tt < NT; ++tt) {
    int p = tt & 1;
    if (tt + 1 < NT) {                  // stage next tile into other buffer
      int kb = (tt + 1) << 6;
#pragma unroll
      for (int j = 0; j < 4; j++) {
        gload_lds16(Ab + (size_t)j * 8 * K + kb,
                    (char*)As + (p ^ 1) * 32768 + w * 4096 + j * 1024);
        gload_lds16(Bb + (size_t)j * 8 * K + kb,
                    (char*)Bs + (p ^ 1) * 32768 + w * 4096 + j * 1024);
      }
    }
    const bf16* Asp = As[p];
    const bf16* Bsp = Bs[p];
    bf16x8 b0[4], b1[4];
#pragma unroll
    for (int nt = 0; nt < 4; nt++) {
      b0[nt] = *(const bf16x8*)&Bsp[rbb + nt * 1024 + co0];
      b1[nt] = *(const bf16x8*)&Bsp[rbb + nt * 1024 + co1];
    }
    __builtin_amdgcn_s_setprio(1);
#pragma unroll
    for (int mt = 0; mt < 8; mt++) {
      bf16x8 a0 = *(const bf16x8*)&Asp[rba + mt * 1024 + co0];
      bf16x8 a1 = *(const bf16x8*)&Asp[rba + mt * 1024 + co1];
#pragma unroll
      for (int nt = 0; nt < 4; nt++) {
        acc[mt][nt] = __builtin_amdgcn_mfma_f32_16x16x32_bf16(a0, b0[nt], acc[mt][nt], 0, 0, 0);
        acc[mt][nt] = __builtin_amdgcn_mfma_f32_16x16x32_bf16(a1, b1[nt], acc[mt][nt], 0, 0, 0);
      }
    }
    __builtin_amdgcn_s_setprio(0);
    __syncthreads();   // drains vmcnt (next tile landed) + read-protect
  }

  // epilogue: D[row=(l>>4)*4+r][col=l&15] per 16x16 tile
#pragma unroll
  for (int mt = 0; mt < 8; mt++)
#pragma unroll
    for (int nt = 0; nt < 4; nt++) {
      int col = n0 + wc * 64 + nt * 16 + l16;
      float bval = bias[col];
      if constexpr (SCATTER) {
        int which = col >> 10;
        int h = (col >> 6) & 15;
        int dh = col & 63;
        int rmask = (1 << rpb) - 1;
        if (which == 2) {
          int rw0 = m0 + wr * 128 + mt * 16 + l4 * 4;
          int b = rw0 >> rpb;
          int s = soff + (rw0 & rmask);
          bf16x4 o;
#pragma unroll
          for (int r = 0; r < 4; r++) o[r] = (bf16)(acc[mt][nt][r] + bval);
          *(bf16x4*)(vs + ((size_t)(b * NHEAD + h) * DHEAD + dh) * S_SEQ + s) = o;
        } else {
          bf16* dst = which == 0 ? qs : ks;
#pragma unroll
          for (int r = 0; r < 4; r++) {
            int rw = m0 + wr * 128 + mt * 16 + l4 * 4 + r;
            int b = rw >> rpb;
            int s = soff + (rw & rmask);
            dst[((size_t)(b * NHEAD + h) * S_SEQ + s) * DHEAD + dh] =
                (bf16)(acc[mt][nt][r] + bval);
          }
        }
      } else {
#pragma unroll
        for (int r = 0; r < 4; r++) {
          int rw = m0 + wr * 128 + mt * 16 + l4 * 4 + r;
          Cp[(size_t)rw * N + col] = (bf16)(acc[mt][nt][r] + bval);
        }
      }
    }
}

// ---------------------------------------------------------------- qkv post
// One block per token (9216). In-place on head-major q/k slabs: rmsnorm over
// D=1024, RoPE via precomputed table (x tokens only), relu; key-mask on k.
__global__ __launch_bounds__(256) void qkv_post(
    bf16* __restrict__ qs, bf16* __restrict__ ks,
    const int* __restrict__ mask, const float* __restrict__ rope,
    const int* __restrict__ anym,
    const float* __restrict__ g_q, const float* __restrict__ g_k,
    const float* __restrict__ cg_q, const float* __restrict__ cg_k) {
  int g = blockIdx.x, t = threadIdx.x;
  bool is_ctx = g >= NBATCH * L_SEQ;
  int b, s;
  const float *gq, *gk;
  float mval;
  if (!is_ctx) {
    b = g >> 11;
    int l = g & 2047;
    s = l;
    mval = mask[(size_t)b * L_SEQ * L_SEQ + l] ? 1.f : 0.f;  // mask[b][0][l]
    gq = g_q; gk = g_k;
  } else {
    int gg = g - NBATCH * L_SEQ;
    b = gg >> 8;
    s = L_SEQ + (gg & 255);
    mval = anym[b] ? 1.f : 0.f;
    gq = cg_q; gk = cg_k;
  }
  int d0 = t * 4;
  int h = t >> 4, dh = (t & 15) * 4;            // h*64+dh == d0
  size_t base = ((size_t)(b * NHEAD + h) * S_SEQ + s) * DHEAD + dh;
  bf16x4 q4 = *(const bf16x4*)(qs + base);
  bf16x4 k4 = *(const bf16x4*)(ks + base);
  float qv[4], kv[4], pq = 0.f, pk = 0.f;
#pragma unroll
  for (int i = 0; i < 4; i++) {
    qv[i] = (float)q4[i]; kv[i] = (float)k4[i];
    pq += qv[i] * qv[i];  pk += kv[i] * kv[i];
  }
  int lane = t & 63, w = t >> 6;
  for (int off = 32; off > 0; off >>= 1) {
    pq += __shfl_down(pq, off, 64);
    pk += __shfl_down(pk, off, 64);
  }
  __shared__ float red[8];
  if (lane == 0) { red[w] = pq; red[4 + w] = pk; }
  __syncthreads();
  float sq = red[0] + red[1] + red[2] + red[3];
  float sk = red[4] + red[5] + red[6] + red[7];
  float scq = rsqrtf(sq * (1.f / DMODEL) + RMS_EPS);
  float sck = rsqrtf(sk * (1.f / DMODEL) + RMS_EPS);
#pragma unroll
  for (int i = 0; i < 4; i++) {
    qv[i] *= scq * gq[d0 + i];
    kv[i] *= sck * gk[d0 + i];
  }
  if (!is_ctx) {
    // table: {cos(fi0),sin(fi0),cos(fi0+1),sin(fi0+1)} at tok*64 + dh
    floatx4 tb4 = *(const floatx4*)&rope[((size_t)(b << 11 | s)) * 64 + dh];
#pragma unroll
    for (int pr = 0; pr < 2; pr++) {
      float cc = tb4[2 * pr], ss = tb4[2 * pr + 1];
      float t0 = qv[2 * pr], t1 = qv[2 * pr + 1];
      qv[2 * pr]     = t0 * cc - t1 * ss;
      qv[2 * pr + 1] = t0 * ss + t1 * cc;
      t0 = kv[2 * pr]; t1 = kv[2 * pr + 1];
      kv[2 * pr]     = t0 * cc - t1 * ss;
      kv[2 * pr + 1] = t0 * ss + t1 * cc;
    }
  }
  bf16x4 qo, ko;
#pragma unroll
  for (int i = 0; i < 4; i++) {
    qo[i] = (bf16)fmaxf(qv[i], 0.f);
    ko[i] = (bf16)(fmaxf(kv[i], 0.f) * mval);
  }
  *(bf16x4*)(qs + base) = qo;
  *(bf16x4*)(ks + base) = ko;
}

// ---------------------------------------------------------------- vk (MFMA)
// vk[bh][e][d] = sum_s vT[bh][e][s] * kf[bh][s][d]; row e=64: sum_s kf[s][d].
// 1-barrier reg-staged double-buffer. Partials atomicAdd into zeroed vkw.
#define VK_CH   8
#define VK_SPAN (S_SEQ / VK_CH)   // 288 = 9 K-steps of 32
__global__ __launch_bounds__(256) void vk_mfma(
    const bf16* __restrict__ vT, const bf16* __restrict__ kf,
    float* __restrict__ vk) {
  __shared__ bf16 Vs[2][64][40];
  __shared__ bf16 Ks[2][64][40];   // Ks[d][s]
  int bh = blockIdx.x >> 3, chunk = blockIdx.x & 7;
  int t = threadIdx.x, lane = t & 63, w = t >> 6;
  int l16 = lane & 15, l4 = lane >> 4;
  const bf16* vp = vT + (size_t)bh * DHEAD * S_SEQ;
  const bf16* kp = kf + (size_t)bh * S_SEQ * DHEAD;
  int s_begin = chunk * VK_SPAN;
  int ve = t >> 2, vso = (t & 3) * 8;        // v staging: row e, col offset
  int ks_s = t & 31, kd0 = (t >> 5) * 8;     // kf staging: s-slice, d-octet
  floatx4 acc[4] = {};
  float dsum[8] = {};
  bf16x8 vv = *(const bf16x8*)(vp + (size_t)ve * S_SEQ + s_begin + vso);
  bf16x8 kv = *(const bf16x8*)(kp + (size_t)(s_begin + ks_s) * DHEAD + kd0);
  for (int st = 0; st < VK_SPAN; st += 32) {
    int cur = (st >> 5) & 1;
    *(bf16x8*)&Vs[cur][ve][vso] = vv;
#pragma unroll
    for (int j = 0; j < 8; j++) {
      Ks[cur][kd0 + j][ks_s] = kv[j];
      dsum[j] += (float)kv[j];
    }
    if (st + 32 < VK_SPAN) {
      int s0 = s_begin + st + 32;
      vv = *(const bf16x8*)(vp + (size_t)ve * S_SEQ + s0 + vso);
      kv = *(const bf16x8*)(kp + (size_t)(s0 + ks_s) * DHEAD + kd0);
    }
    __syncthreads();
    bf16x8 af = *(const bf16x8*)&Vs[cur][w * 16 + l16][l4 * 8];
#pragma unroll
    for (int nt = 0; nt < 4; nt++) {
      bf16x8 bfr = *(const bf16x8*)&Ks[cur][nt * 16 + l16][l4 * 8];
      acc[nt] = __builtin_amdgcn_mfma_f32_16x16x32_bf16(af, bfr, acc[nt], 0, 0, 0);
    }
  }
  float* vkbh = vk + (size_t)bh * 65 * 64;
#pragma unroll
  for (int nt = 0; nt < 4; nt++)
#pragma unroll
    for (int r = 0; r < 4; r++)
      atomicAdd(&vkbh[(w * 16 + l4 * 4 + r) * 64 + nt * 16 + l16], acc[nt][r]);
#pragma unroll
  for (int j = 0; j < 8; j++)
#pragma unroll
    for (int off = 16; off > 0; off >>= 1)
      dsum[j] += __shfl_down(dsum[j], off, 32);
  if ((lane & 31) == 0)
#pragma unroll
    for (int j = 0; j < 8; j++)
      atomicAdd(&vkbh[64 * 64 + kd0 + j], dsum[j]);
}

// ---------------------------------------------------------------- res + div
// res[q][e] = sum_d qf[q][d]*vk[e][d]; attn = res[:,:64]/(res[:,64]+eps).
__global__ __launch_bounds__(256) void res_attn(
    const bf16* __restrict__ qf, const float* __restrict__ vk,
    bf16* __restrict__ attn_x, bf16* __restrict__ attn_c) {
  __shared__ bf16 Bs[80][72];
  __shared__ float sden[256];
  int bh = blockIdx.x / 9, mblk = blockIdx.x % 9;
  int b = bh >> 4, h = bh & 15;
  int t = threadIdx.x, lane = t & 63, w = t >> 6;
  const float* vkp = vk + (size_t)bh * 65 * 64;
  for (int i = t; i < 80 * 64; i += 256) {
    int e = i >> 6, d = i & 63;
    Bs[e][d] = (bf16)(e < 65 ? vkp[i] : 0.f);
  }
  __syncthreads();
  int l16 = lane & 15, l4 = lane >> 4;
  const bf16* qbase = qf + (size_t)bh * S_SEQ * DHEAD;
  int q0w = mblk * 256 + w * 64;

  floatx4 acc[4][5] = {};
  bf16x8 af[4][2], bfr[5][2];
#pragma unroll
  for (int mt = 0; mt < 4; mt++) {
    int q = q0w + mt * 16 + l16;
    af[mt][0] = *(const bf16x8*)(qbase + (size_t)q * 64 + l4 * 8);
    af[mt][1] = *(const bf16x8*)(qbase + (size_t)q * 64 + 32 + l4 * 8);
  }
#pragma unroll
  for (int nt = 0; nt < 5; nt++) {
    bfr[nt][0] = *(const bf16x8*)&Bs[nt * 16 + l16][l4 * 8];
    bfr[nt][1] = *(const bf16x8*)&Bs[nt * 16 + l16][32 + l4 * 8];
  }
#pragma unroll
  for (int mt = 0; mt < 4; mt++)
#pragma unroll
    for (int nt = 0; nt < 5; nt++) {
      acc[mt][nt] = __builtin_amdgcn_mfma_f32_16x16x32_bf16(af[mt][0], bfr[nt][0], acc[mt][nt], 0, 0, 0);
      acc[mt][nt] = __builtin_amdgcn_mfma_f32_16x16x32_bf16(af[mt][1], bfr[nt][1], acc[mt][nt], 0, 0, 0);
    }
  // denominator: e=64 = col 0 of n-tile 4 (lanes with l16==0)
  if (l16 == 0) {
#pragma unroll
    for (int mt = 0; mt < 4; mt++)
#pragma unroll
      for (int r = 0; r < 4; r++)
        sden[w * 64 + mt * 16 + l4 * 4 + r] = acc[mt][4][r];
  }
  __syncthreads();
#pragma unroll
  for (int mt = 0; mt < 4; mt++)
#pragma unroll
    for (int r = 0; r < 4; r++) {
      float den = sden[w * 64 + mt * 16 + l4 * 4 + r] + LIN_EPS;
      float rden = 1.f / den;
      int q = q0w + mt * 16 + l4 * 4 + r;
#pragma unroll
      for (int nt = 0; nt < 4; nt++) {
        int dcol = nt * 16 + l16;
        float a = acc[mt][nt][r] * rden;
        if (q < L_SEQ)
          attn_x[((size_t)b * L_SEQ + q) * DMODEL + h * DHEAD + dcol] = (bf16)a;
        else
          attn_c[((size_t)b * C_SEQ + (q - L_SEQ)) * DMODEL + h * DHEAD + dcol] = (bf16)a;
      }
    }
}

// ---------------------------------------------------------------- final norm
// Reads bf16 y, writes FLOAT32 output (the reference's output dtype).
__global__ __launch_bounds__(256) void final_norm(
    const bf16* __restrict__ y_x, const bf16* __restrict__ y_c,
    const float* __restrict__ g_out, const float* __restrict__ cg_out,
    float* __restrict__ out) {
  int g = blockIdx.x, t = threadIdx.x;
  const bf16* src;
  const float* gv;
  if (g < NBATCH * L_SEQ) {
    src = y_x + (size_t)g * DMODEL; gv = g_out;
  } else {
    int gg = g - NBATCH * L_SEQ;
    src = y_c + (size_t)gg * DMODEL; gv = cg_out;
  }
  float* dst = out + (size_t)g * DMODEL;
  int d0 = t * 4;
  bf16x4 y4 = *(const bf16x4*)(src + d0);
  float yv[4], p = 0.f;
#pragma unroll
  for (int i = 0; i < 4; i++) { yv[i] = (float)y4[i]; p += yv[i] * yv[i]; }
  int lane = t & 63, w = t >> 6;
  for (int off = 32; off > 0; off >>= 1) p += __shfl_down(p, off, 64);
  __shared__ float red[4];
  if (lane == 0) red[w] = p;
  __syncthreads();
  float ssum = red[0] + red[1] + red[2] + red[3];
  float sc = rsqrtf(ssum * (1.f / DMODEL) + RMS_EPS);
  floatx4 o;
#pragma unroll
  for (int i = 0; i < 4; i++) o[i] = yv[i] * sc * gv[d0 + i];
  *(floatx4*)(dst + d0) = o;
}

// ---------------------------------------------------------------- launch
extern "C" void kernel_launch(void* const* d_in, const int* in_sizes, int n_in,
                              void* d_out, int out_size, void* d_ws, size_t ws_size,
                              hipStream_t stream) {
  const float* x      = (const float*)d_in[0];
  const float* ctx    = (const float*)d_in[1];
  const int*   mask   = (const int*)d_in[2];
  const int*   spos   = (const int*)d_in[3];
  const float* Wqkv   = (const float*)d_in[4];
  const float* bqkv   = (const float*)d_in[5];
  const float* g_q    = (const float*)d_in[6];
  const float* g_k    = (const float*)d_in[7];
  const float* cWqkv  = (const float*)d_in[8];
  const float* cbqkv  = (const float*)d_in[9];
  const float* cg_q   = (const float*)d_in[10];
  const float* cg_k   = (const float*)d_in[11];
  const float* Wout   = (const float*)d_in[12];
  const float* bout   = (const float*)d_in[13];
  const float* g_out  = (const float*)d_in[14];
  const float* cWout  = (const float*)d_in[15];
  const float* cbout  = (const float*)d_in[16];
  const float* cg_out = (const float*)d_in[17];

  char* wsp = (char*)d_ws;
  size_t off = 0;
  auto alloc = [&](size_t bytes) -> void* {
    void* p = wsp + off;
    off += (bytes + 255) & ~(size_t)255;
    return p;
  };
  bf16* WqkvT  = (bf16*)alloc((size_t)3072 * 1024 * 2);
  bf16* cWqkvT = (bf16*)alloc((size_t)3072 * 1024 * 2);
  bf16* WoutT  = (bf16*)alloc((size_t)1024 * 1024 * 2);
  bf16* cWoutT = (bf16*)alloc((size_t)1024 * 1024 * 2);
  bf16* xbf    = (bf16*)alloc((size_t)NBATCH * L_SEQ * DMODEL * 2);
  bf16* cbf    = (bf16*)alloc((size_t)NBATCH * C_SEQ * DMODEL * 2);
  const size_t SLAB = (size_t)NBATCH * NHEAD * S_SEQ * DHEAD;  // 9,437,184
  bf16* qfs    = (bf16*)alloc(SLAB * 2);
  bf16* kfs    = (bf16*)alloc(SLAB * 2);
  bf16* vfs    = (bf16*)alloc(SLAB * 2);   // holds vT [bh][d][s]
  float* vkw   = (float*)alloc((size_t)64 * 65 * 64 * 4);
  float* rope  = (float*)alloc((size_t)NBATCH * L_SEQ * 64 * 4);
  int* anym    = (int*)alloc(256);
  // attn aliases kf slab (dead after vk_mfma); y aliases v slab.
  bf16* attn_x = kfs;
  bf16* attn_c = kfs + (size_t)NBATCH * L_SEQ * DMODEL;
  bf16* y_x    = vfs;
  bf16* y_c    = vfs + (size_t)NBATCH * L_SEQ * DMODEL;

  // 1) fused prep: transposes, converts, vkw zero, rope table, anymask
  prep<<<15112, 256, 0, stream>>>(Wqkv, cWqkv, Wout, cWout, x, ctx, mask, spos,
                                  WqkvT, cWqkvT, WoutT, cWoutT, xbf, cbf,
                                  vkw, rope, anym);

  // 2) QKV projections (x + ctx in one launch) -> head-major q/k + vT slabs
  gemm_bias<true><<<dim3(12, 36), 512, 0, stream>>>(
      xbf, cbf, WqkvT, cWqkvT, bqkv, cbqkv, nullptr, nullptr,
      qfs, kfs, vfs, 3072, 1024, 32, 11, 0, 8, L_SEQ);

  // 3) in-place rmsnorm + rope + relu + mask on q/k slabs
  qkv_post<<<NBATCH * (L_SEQ + C_SEQ), 256, 0, stream>>>(
      qfs, kfs, mask, rope, anym, g_q, g_k, cg_q, cg_k);

  // 4) vk = vT kf via MFMA
  vk_mfma<<<64 * VK_CH, 256, 0, stream>>>(vfs, kfs, vkw);

  // 5) res = qf vk^T, divide, scatter to token-major (B,S,D)
  res_attn<<<576, 256, 0, stream>>>(qfs, vkw, attn_x, attn_c);

  // 6) output projections (x + ctx in one launch)
  gemm_bias<false><<<dim3(4, 36), 512, 0, stream>>>(
      attn_x, attn_c, WoutT, cWoutT, bout, cbout, y_x, y_c,
      nullptr, nullptr, nullptr, 1024, 1024, 32, 0, 0, 0, 0);

  // 7) final rmsnorm -> FLOAT32 d_out (x_out rows then c_out rows)
  final_norm<<<NBATCH * (L_SEQ + C_SEQ), 256, 0, stream>>>(
      y_x, y_c, g_out, cg_out, (float*)d_out);
}